// Round 25
// baseline (416.784 us; speedup 1.0000x reference)
//
#include <hip/hip_runtime.h>

#define DEV __device__ __forceinline__

typedef short  bf16x8 __attribute__((ext_vector_type(8)));
typedef float  f32x4  __attribute__((ext_vector_type(4)));

DEV unsigned short f2b(float f) {
    unsigned int u = __float_as_uint(f);
    u += 0x7fffu + ((u >> 16) & 1u);
    return (unsigned short)(u >> 16);
}
DEV float b2f(unsigned short h) { return __uint_as_float((unsigned int)h << 16); }
DEV float silu(float x) { return x / (1.f + __expf(-x)); }
DEV float fexp2(float x) { return __builtin_amdgcn_exp2f(x); }   // raw v_exp_f32
DEV float flog2(float x) { return __builtin_amdgcn_logf(x); }    // raw v_log_f32

// async global->LDS, 16B per lane: HW writes lane l at ldsbase + l*16
typedef const __attribute__((address_space(1))) unsigned int GU32;
typedef __attribute__((address_space(3))) unsigned int LU32;
DEV void gload16(const unsigned short* g, unsigned short* l) {
    __builtin_amdgcn_global_load_lds((GU32*)g, (LU32*)l, 16, 0, 0);
}

// ---------------------------------------------------------------------------
// fused prep: weight f32->bf16 conversions + dt_proj_w split-bf16 packing +
// scan A2 table (-exp(A_log)*log2e) with integer-power flag.
__global__ __launch_bounds__(256) void k_prep(
        const float* __restrict__ x, const float* __restrict__ merge_w,
        const float* __restrict__ in_proj_w, const float* __restrict__ x_proj_w,
        const float* __restrict__ out_proj_w, const float* __restrict__ dt_proj_w,
        const float* __restrict__ A_log,
        unsigned short* __restrict__ xbf, unsigned short* __restrict__ mw,
        unsigned short* __restrict__ ipw, unsigned short* __restrict__ xpw,
        unsigned short* __restrict__ opw, unsigned short* __restrict__ dtpB,
        float* __restrict__ A2tab, int* __restrict__ powflag) {
    size_t i = (size_t)blockIdx.x * 256 + threadIdx.x;
    const size_t n0 = 524288;           // x: 4096*512/4
    const size_t n1 = n0 + 131072;      // merge_w: 512*1024/4
    const size_t n2 = n1 + 524288;      // in_proj: 2*2048*512/4
    const size_t n3 = n2 + 32768;       // x_proj: 2*64*1024/4
    const size_t n4 = n3 + 262144;      // out_proj: 2*512*1024/4
    const size_t n5 = n4 + 65536;       // dtpackB: 2*1024*32 scalars
    const size_t n6 = n5 + 2048;        // A2 table: one thread per d (2 layers)
    if (i < n4) {
        const float* s; unsigned short* d; size_t j;
        if (i < n0)      { s = x;          d = xbf; j = i; }
        else if (i < n1) { s = merge_w;    d = mw;  j = i - n0; }
        else if (i < n2) { s = in_proj_w;  d = ipw; j = i - n1; }
        else if (i < n3) { s = x_proj_w;   d = xpw; j = i - n2; }
        else             { s = out_proj_w; d = opw; j = i - n3; }
        float4 v = *(const float4*)(s + j * 4);
        ushort4 o = { f2b(v.x), f2b(v.y), f2b(v.z), f2b(v.w) };
        *(ushort4*)(d + j * 4) = o;
    } else if (i < n5) {
        size_t j = i - n4;              // (li*1024+d)*32 + r
        int r = (int)(j & 31);
        size_t dg = j >> 5;             // global d in [0, 2048)
        float xw = dt_proj_w[dg * 32 + r];
        unsigned short wh = f2b(xw);
        unsigned short wl = f2b(xw - b2f(wh));
        size_t base = dg * 128;
        dtpB[base + r]      = wh;
        dtpB[base + 32 + r] = wl;
        dtpB[base + 64 + r] = wl;
        dtpB[base + 96 + r] = wh;
    } else if (i < n6) {
        size_t dg = i - n5;             // [0, 2048)
        constexpr float LOG2E = 1.4426950408889634f;
        float a2[16];
#pragma unroll
        for (int s = 0; s < 16; ++s)
            a2[s] = -expf(A_log[dg * 16 + s]) * LOG2E;
        bool ok = true;
#pragma unroll
        for (int s = 1; s < 16; ++s)
            ok = ok && (fabsf(a2[s] - (float)(s + 1) * a2[0]) <= 1e-5f * fabsf(a2[s]));
#pragma unroll
        for (int s = 0; s < 16; s += 4)
            *(f32x4*)(A2tab + dg * 16 + s) = *(const f32x4*)&a2[s];
        powflag[dg] = ok ? 1 : 0;
    }
}

// up_w (512 x 512 x 4) [i,o,k] -> upT[(k*512+o)*512 + i] bf16
__global__ void k_upT(const float* __restrict__ up_w, unsigned short* __restrict__ upT) {
    __shared__ float t[32][33];
    int tx = threadIdx.x, ty = threadIdx.y;
    int o0 = blockIdx.x * 32, i0 = blockIdx.y * 32, kz = blockIdx.z;
    t[ty][tx] = up_w[(size_t)(i0 + ty) * 2048 + (o0 + tx) * 4 + kz];
    __syncthreads();
    upT[(size_t)(kz * 512 + o0 + ty) * 512 + i0 + tx] = f2b(t[tx][ty]);
}

// ---------------------------------------------------------------------------
// bf16 MFMA GEMM, NT: C[m,n] = sum_k A[m,k]*B[n,k].  BK=64, 4 waves,
// global_load_lds staging with T2 XOR-swizzle (rule #21: linear LDS dest +
// inverse-swizzled GLOBAL source + swizzled READ).
// XCD-aware block swizzle (T1): contiguous tile chunks per XCD for L2 reuse.
// Tiles: (BM,BN) in {(128,128),(128,64),(64,64)}.
// OUTMODE 0: f32 out, 1: bf16 out, 2: softplus->f32, 3: softplus->bf16,
//         4: f32 out + dtpackA for cols<32 (split-bf16 K=128 operand).
template <int BM, int BN, int OUTMODE>
__global__ __launch_bounds__(256) void k_gemm(const unsigned short* __restrict__ A,
                                              const unsigned short* __restrict__ B,
                                              float* __restrict__ Cf,
                                              unsigned short* __restrict__ Cb,
                                              const float* __restrict__ bias,
                                              int M, int N, int K) {
    constexpr int BK = 64;
    constexpr int WM = (BN == 128) ? 64 : 32;
    constexpr int WN = (BM == 64 && BN == 64) ? 32 : 64;
    constexpr int MI = WM / 16, NI = WN / 16;
    __shared__ unsigned short As[BM * BK];
    __shared__ unsigned short Bs[BN * BK];
    const int tid = threadIdx.x;
    const int wid = tid >> 6, lane = tid & 63;

    // XCD swizzle: hw bids round-robin XCDs; map same-XCD bids to contiguous tiles
    int bid = blockIdx.y * gridDim.x + blockIdx.x;
    const int nwg = gridDim.x * gridDim.y;
    if ((nwg & 7) == 0) {
        int cpx = nwg >> 3;
        bid = (bid & 7) * cpx + (bid >> 3);
    }
    const int bx = bid % gridDim.x, by = bid / gridDim.x;
    const int m0 = by * BM, n0 = bx * BN;

    int wr, wc;
    if (BN == 128)      { wr = wid >> 1; wc = wid & 1; }
    else if (BM == 128) { wr = wid;      wc = 0;       }
    else                { wr = wid & 1;  wc = wid >> 1; }
    const int wm0 = wr * WM, wn0 = wc * WN;
    const int fr = lane & 15, fh = lane >> 4;

    // staging (BK=64): one gload16 covers 8 rows; lane l -> row (l>>3).
    // Global source col chunk pre-swizzled: chunk = (l&7) ^ (l>>3), because
    // staged rows step by 32 so (row & 7) == (l>>3) for this lane always.
    const int srow = lane >> 3;
    const int scol = (((lane & 7) ^ srow)) * 8;
    const unsigned short* Ag = A + (size_t)(m0 + wid * 8 + srow) * K + scol;
    const unsigned short* Bg = B + (size_t)(n0 + wid * 8 + srow) * K + scol;
    unsigned short* AsB = &As[wid * 8 * BK];
    unsigned short* BsB = &Bs[wid * 8 * BK];

    f32x4 acc[MI][NI];
#pragma unroll
    for (int i = 0; i < MI; ++i)
#pragma unroll
        for (int j = 0; j < NI; ++j) acc[i][j] = (f32x4){0.f, 0.f, 0.f, 0.f};

    const int frx = fr & 7;   // read-side XOR factor (row & 7)
    for (int k0 = 0; k0 < K; k0 += BK) {
#pragma unroll
        for (int i = 0; i < BM / 32; ++i)
            gload16(Ag + (size_t)(i * 32) * K + k0, AsB + i * 32 * BK);
#pragma unroll
        for (int i = 0; i < BN / 32; ++i)
            gload16(Bg + (size_t)(i * 32) * K + k0, BsB + i * 32 * BK);
        __syncthreads();
#pragma unroll
        for (int kk = 0; kk < BK; kk += 32) {
            bf16x8 av[MI], bv[NI];
#pragma unroll
            for (int mi = 0; mi < MI; ++mi)
                av[mi] = *(const bf16x8*)(&As[(wm0 + mi * 16 + fr) * BK +
                                              ((((kk >> 3) + fh) ^ frx) << 3)]);
#pragma unroll
            for (int ni = 0; ni < NI; ++ni)
                bv[ni] = *(const bf16x8*)(&Bs[(wn0 + ni * 16 + fr) * BK +
                                              ((((kk >> 3) + fh) ^ frx) << 3)]);
#pragma unroll
            for (int mi = 0; mi < MI; ++mi)
#pragma unroll
                for (int ni = 0; ni < NI; ++ni)
                    acc[mi][ni] = __builtin_amdgcn_mfma_f32_16x16x32_bf16(av[mi], bv[ni],
                                                                          acc[mi][ni], 0, 0, 0);
        }
        __syncthreads();
    }
    constexpr float LOG2E = 1.4426950408889634f;
    constexpr float LN2   = 0.6931471805599453f;
#pragma unroll
    for (int mi = 0; mi < MI; ++mi) {
#pragma unroll
        for (int ni = 0; ni < NI; ++ni) {
            int col = n0 + wn0 + ni * 16 + fr;
            float bb = bias ? bias[col] : 0.f;
#pragma unroll
            for (int j = 0; j < 4; ++j) {
                int row = m0 + wm0 + mi * 16 + fh * 4 + j;
                float v = acc[mi][ni][j] + bb;
                if (OUTMODE == 0)      Cf[(size_t)row * N + col] = v;
                else if (OUTMODE == 1) Cb[(size_t)row * N + col] = f2b(v);
                else if (OUTMODE == 4) {
                    Cf[(size_t)row * N + col] = v;
                    if (col < 32) {
                        unsigned short xh = f2b(v);
                        unsigned short xl = f2b(v - b2f(xh));
                        size_t base = (size_t)row * 128;
                        Cb[base + col]      = xh;
                        Cb[base + 32 + col] = xl;
                        Cb[base + 64 + col] = xh;
                        Cb[base + 96 + col] = xl;
                    }
                } else {
                    float sp = (v > 20.f) ? v : flog2(1.f + fexp2(v * LOG2E)) * LN2;
                    if (OUTMODE == 2) Cf[(size_t)row * N + col] = sp;
                    else              Cb[(size_t)row * N + col] = f2b(sp);
                }
            }
        }
    }
}

// ---------------------------------------------------------------------------
// assemble cat row-major (8192 x 1024) bf16: [0,512)=xu from P(bf16), rest=skip
__global__ __launch_bounds__(256) void k_assemble(const unsigned short* __restrict__ P,
                                                  const float* __restrict__ skip,
                                                  const float* __restrict__ up_b,
                                                  unsigned short* __restrict__ catbf) {
    int bx = blockIdx.x;
    int m = bx >> 2;
    int c = (bx & 3) * 256 + threadIdx.x;
    int b = m >> 10, t = m & 1023, j = t >> 1;
    float v;
    if (c < 512) {
        size_t rb = (size_t)((b << 9) + j) * 2048;
        if (t & 1) {                       // odd t: k=2 @ j, k=0 @ j+1
            v = b2f(P[rb + 1024 + c]);
            if (j + 1 < 512) v += b2f(P[rb + 2048 + c]);
        } else {                           // even t: k=3 @ j-1, k=1 @ j
            v = b2f(P[rb + 512 + c]);
            if (j >= 1) v += b2f(P[rb - 2048 + 1536 + c]);
        }
        v += up_b[c];
    } else {
        v = skip[(size_t)m * 512 + (c - 512)];
    }
    catbf[(size_t)m * 1024 + c] = f2b(v);
}

// LayerNorm over 512 (bf16 input), 4 rows per 256-block, writes bf16
__global__ __launch_bounds__(256) void k_ln(const unsigned short* __restrict__ merged,
                                            const float* __restrict__ w,
                                            const float* __restrict__ bvec,
                                            unsigned short* __restrict__ outb) {
    int row = blockIdx.x * 4 + (threadIdx.x >> 6);
    int lane = threadIdx.x & 63;
    const unsigned short* r = merged + (size_t)row * 512 + lane * 8;
    bf16x8 v = *(const bf16x8*)r;
    float xv[8];
#pragma unroll
    for (int e = 0; e < 8; ++e) xv[e] = b2f((unsigned short)v[e]);
    float s = 0.f, ss = 0.f;
#pragma unroll
    for (int e = 0; e < 8; ++e) { s += xv[e]; ss += xv[e] * xv[e]; }
#pragma unroll
    for (int m = 1; m < 64; m <<= 1) { s += __shfl_xor(s, m, 64); ss += __shfl_xor(ss, m, 64); }
    float mean = s * (1.f / 512.f);
    float var = ss * (1.f / 512.f) - mean * mean;
    float inv = rsqrtf(var + 1e-5f);
    unsigned short o8[8];
#pragma unroll
    for (int e = 0; e < 8; ++e) {
        int c = lane * 8 + e;
        o8[e] = f2b((xv[e] - mean) * inv * w[c] + bvec[c]);
    }
    *(int4*)(outb + (size_t)row * 512 + lane * 8) = *(const int4*)o8;
}

// causal depthwise conv K=4 + bias + silu; 4 channels/thread, bf16 in/out
__global__ __launch_bounds__(256) void k_conv(const unsigned short* __restrict__ xzb,
                                              const float* __restrict__ cw,
                                              const float* __restrict__ cb,
                                              unsigned short* __restrict__ xcb) {
    int i = blockIdx.x * 256 + threadIdx.x;   // 2.1M threads
    int m = i >> 8;
    int c0 = (i & 255) * 4;
    int l = m & 1023;
    float4 w0 = *(const float4*)(cw + (size_t)(c0 + 0) * 4);
    float4 w1 = *(const float4*)(cw + (size_t)(c0 + 1) * 4);
    float4 w2 = *(const float4*)(cw + (size_t)(c0 + 2) * 4);
    float4 w3 = *(const float4*)(cw + (size_t)(c0 + 3) * 4);
    float4 acc = *(const float4*)(cb + c0);
    const float* wp0 = (const float*)&w0;
    const float* wp1 = (const float*)&w1;
    const float* wp2 = (const float*)&w2;
    const float* wp3 = (const float*)&w3;
#pragma unroll
    for (int k = 0; k < 4; ++k) {
        int lp = l - 3 + k;
        if (lp >= 0) {
            ushort4 xv = *(const ushort4*)(xzb + (size_t)(m - l + lp) * 2048 + c0);
            acc.x = fmaf(wp0[k], b2f(xv.x), acc.x);
            acc.y = fmaf(wp1[k], b2f(xv.y), acc.y);
            acc.z = fmaf(wp2[k], b2f(xv.z), acc.z);
            acc.w = fmaf(wp3[k], b2f(xv.w), acc.w);
        }
    }
    ushort4 o = { f2b(silu(acc.x)), f2b(silu(acc.y)), f2b(silu(acc.z)), f2b(silu(acc.w)) };
    *(ushort4*)(xcb + (size_t)m * 1024 + c0) = o;
}

// ---------------------------------------------------------------------------
// Chunked selective scan.  L=1024 split into NC=32 chunks of CL=32.
// Thread = (b, d, chunk), 16 states in registers.  dt/u staged in LDS;
// A2 row + power flag loaded from precomputed table (k_prep).
// ILP: powers of a1 computed as a TREE (depth 4, not a 16-deep chain);
// phase-1 p accumulated in 4 partials.
// Summaries COMPRESSED: phase0 stores packed uint32 (bf16 a | bf16 h << 16);
// carry writes compact bf16 h_init; phase1 reads bf16 h_init.
constexpr int SCAN_NC = 32;
constexpr int SCAN_CL = 32;

template <int PHASE>
__global__ __launch_bounds__(256) void k_scan_chunk(
        const unsigned short* __restrict__ dtb, const unsigned short* __restrict__ xcb,
        const float* __restrict__ xdbl, const unsigned short* __restrict__ xzb,
        const float* __restrict__ A2tab, const int* __restrict__ powflag,
        const float* __restrict__ Dp,
        unsigned int* __restrict__ sum, const unsigned short* __restrict__ hinit,
        unsigned short* __restrict__ ybf) {
    constexpr int CL = SCAN_CL;
    const int tid = threadIdx.x;
    const int d0 = blockIdx.x * 256;
    const int d = d0 + tid;
    const int b = blockIdx.y, c = blockIdx.z;
    const size_t mbase = (size_t)b * 1024 + (size_t)c * CL;

    // bulk-stage chunk inputs into LDS (coalesced 16B chunks, all in flight):
    //   sBC: B/C slice of xdbl; sdt/su: this block's dt/u [CL][256] bf16.
    __shared__ float sBC[CL][32];
    __shared__ unsigned short sdt[CL][256];
    __shared__ unsigned short su[CL][256];
    {
        int row = tid >> 3, q = tid & 7;   // CL*8 == 256
        *(float4*)&sBC[row][q * 4] =
            *(const float4*)(xdbl + (mbase + row) * 64 + 32 + q * 4);
    }
    for (int i = tid; i < CL * 32; i += 256) {       // 32 rows x 32 16B-chunks
        int row = i >> 5, q = i & 31;
        const size_t g = (mbase + row) * 1024 + d0 + q * 8;
        *(int4*)&sdt[row][q * 8] = *(const int4*)(dtb + g);
        *(int4*)&su[row][q * 8]  = *(const int4*)(xcb + g);
    }
    __syncthreads();

    float A2[16], h[16];
#pragma unroll
    for (int s = 0; s < 16; s += 4)
        *(f32x4*)&A2[s] = *(const f32x4*)(A2tab + (size_t)d * 16 + s);
    const bool powok = powflag[d] != 0;

    const size_t sumbase = ((size_t)(b * SCAN_NC + c) << 14) + d * 16;
    if (PHASE == 0) {
#pragma unroll
        for (int s = 0; s < 16; ++s) h[s] = 0.f;
    } else {
#pragma unroll
        for (int s = 0; s < 16; s += 8) {
            bf16x8 hv = *(const bf16x8*)(hinit + sumbase + s);
#pragma unroll
            for (int j = 0; j < 8; ++j) h[s + j] = b2f((unsigned short)hv[j]);
        }
    }
    float dtsum = 0.f;
    const float Dv = (PHASE == 1) ? Dp[d] : 0.f;

    // z prefetch one step ahead (phase 1 only)
    float zv_n = 0.f;
    if (PHASE == 1) zv_n = b2f(xzb[mbase * 2048 + 1024 + d]);

#pragma unroll 2
    for (int l = 0; l < CL; ++l) {
        const size_t m = mbase + l;
        const float dtv_c = b2f(sdt[l][tid]);
        const float uv_c  = b2f(su[l][tid]);
        float zv;
        if (PHASE == 1) {
            zv = zv_n;
            if (l + 1 < CL) zv_n = b2f(xzb[(m + 1) * 2048 + 1024 + d]);
        }
        const float dtu = dtv_c * uv_c;
        if (PHASE == 0) dtsum += dtv_c;
        float Bv[16], Cv[16];
#pragma unroll
        for (int q = 0; q < 4; ++q) {
            *(float4*)&Bv[q * 4] = *(const float4*)&sBC[l][q * 4];
            if (PHASE == 1)
                *(float4*)&Cv[q * 4] = *(const float4*)&sBC[l][16 + q * 4];
        }
        float p = 0.f;
        if (powok) {
            const float a1 = fexp2(dtv_c * A2[0]);
            const float a2 = a1 * a1, a3 = a2 * a1, a4 = a2 * a2;
            const float a5 = a4 * a1, a6 = a4 * a2, a7 = a4 * a3, a8 = a4 * a4;
            const float aa[16] = { a1, a2, a3, a4, a5, a6, a7, a8,
                                   a8 * a1, a8 * a2, a8 * a3, a8 * a4,
                                   a8 * a5, a8 * a6, a8 * a7, a8 * a8 };
#pragma unroll
            for (int s = 0; s < 16; ++s)
                h[s] = fmaf(aa[s], h[s], dtu * Bv[s]);
            if (PHASE == 1) {
                float p0 = 0.f, p1 = 0.f, p2 = 0.f, p3 = 0.f;
#pragma unroll
                for (int s = 0; s < 4; ++s) {
                    p0 = fmaf(h[s],      Cv[s],      p0);
                    p1 = fmaf(h[s + 4],  Cv[s + 4],  p1);
                    p2 = fmaf(h[s + 8],  Cv[s + 8],  p2);
                    p3 = fmaf(h[s + 12], Cv[s + 12], p3);
                }
                p = (p0 + p1) + (p2 + p3);
            }
        } else {
#pragma unroll
            for (int s = 0; s < 16; ++s) {
                float a = fexp2(dtv_c * A2[s]);
                h[s] = fmaf(a, h[s], dtu * Bv[s]);
                if (PHASE == 1) p = fmaf(h[s], Cv[s], p);
            }
        }
        if (PHASE == 1) {
            ybf[m * 1024 + d] = f2b((p + Dv * uv_c) * silu(zv));
        }
    }
    if (PHASE == 0) {
        float aprod[16];
        if (powok) {
            const float g1 = fexp2(A2[0] * dtsum);
            const float g2 = g1 * g1, g3 = g2 * g1, g4 = g2 * g2;
            const float g5 = g4 * g1, g6 = g4 * g2, g7 = g4 * g3, g8 = g4 * g4;
            aprod[0] = g1;  aprod[1] = g2;  aprod[2] = g3;  aprod[3] = g4;
            aprod[4] = g5;  aprod[5] = g6;  aprod[6] = g7;  aprod[7] = g8;
            aprod[8]  = g8 * g1;  aprod[9]  = g8 * g2;
            aprod[10] = g8 * g3;  aprod[11] = g8 * g4;
            aprod[12] = g8 * g5;  aprod[13] = g8 * g6;
            aprod[14] = g8 * g7;  aprod[15] = g8 * g8;
        } else {
#pragma unroll
            for (int s = 0; s < 16; ++s) aprod[s] = fexp2(A2[s] * dtsum);
        }
        unsigned int pk[16];
#pragma unroll
        for (int s = 0; s < 16; ++s)
            pk[s] = (unsigned int)f2b(aprod[s]) | ((unsigned int)f2b(h[s]) << 16);
#pragma unroll
        for (int s = 0; s < 16; s += 4)
            *(uint4*)(sum + sumbase + s) = *(const uint4*)&pk[s];
    }
}

// carry scan over packed chunk summaries; writes compact bf16 h_init.
__global__ __launch_bounds__(256) void k_scan_carry(const unsigned int* __restrict__ sum,
                                                    unsigned short* __restrict__ hinit) {
    int i = blockIdx.x * 256 + threadIdx.x;   // (b, d*16+s)
    int b = i >> 14, ds = i & 16383;
    float h = 0.f;
    for (int c = 0; c < SCAN_NC; ++c) {
        size_t idx = ((size_t)(b * SCAN_NC + c) << 14) + ds;
        unsigned int u = sum[idx];
        float a = b2f((unsigned short)(u & 0xffffu));
        float f = b2f((unsigned short)(u >> 16));
        hinit[idx] = f2b(h);
        h = fmaf(a, h, f);
    }
}

// ---------------------------------------------------------------------------
extern "C" void kernel_launch(void* const* d_in, const int* in_sizes, int n_in,
                              void* d_out, int out_size, void* d_ws, size_t ws_size,
                              hipStream_t stream) {
    const float* x         = (const float*)d_in[0];
    const float* skip      = (const float*)d_in[1];
    const float* up_w      = (const float*)d_in[2];
    const float* up_b      = (const float*)d_in[3];
    const float* merge_w   = (const float*)d_in[4];
    const float* merge_b   = (const float*)d_in[5];
    const float* ln_w      = (const float*)d_in[6];
    const float* ln_b      = (const float*)d_in[7];
    const float* in_proj_w = (const float*)d_in[8];
    const float* conv_w    = (const float*)d_in[9];
    const float* conv_b    = (const float*)d_in[10];
    const float* x_proj_w  = (const float*)d_in[11];
    const float* dt_proj_w = (const float*)d_in[12];
    const float* dt_proj_b = (const float*)d_in[13];
    const float* A_log     = (const float*)d_in[14];
    const float* D_param   = (const float*)d_in[15];
    const float* out_proj_w= (const float*)d_in[16];
    float* out = (float*)d_out;

    char* ws = (char*)d_ws;
    size_t off = 0;
    auto alloc = [&](size_t bytes) { size_t r = off; off += (bytes + 255) & ~(size_t)255; return r; };

    // persistent
    unsigned short* upT  = (unsigned short*)(ws + alloc(2048ull * 512 * 2));
    unsigned short* mw   = (unsigned short*)(ws + alloc(512ull * 1024 * 2));
    unsigned short* ipw  = (unsigned short*)(ws + alloc(2ull * 2048 * 512 * 2));
    unsigned short* xpw  = (unsigned short*)(ws + alloc(2ull * 64 * 1024 * 2));
    unsigned short* opw  = (unsigned short*)(ws + alloc(2ull * 512 * 1024 * 2));
    unsigned short* xbf  = (unsigned short*)(ws + alloc(4096ull * 512 * 2));
    unsigned short* ubf  = (unsigned short*)(ws + alloc(8192ull * 512 * 2));
    float*          A2tab   = (float*)(ws + alloc(2048ull * 16 * 4));
    int*            powflag = (int*)(ws + alloc(2048ull * 4));
    // per-layer arena (stage-1 buffers aliased in)
    unsigned short* xzbf  = (unsigned short*)(ws + alloc(8192ull * 2048 * 2));
    unsigned short* xcbf  = (unsigned short*)(ws + alloc(8192ull * 1024 * 2));
    float*          xdbl  = (float*)(ws + alloc(8192ull * 64 * 4));
    unsigned short* dtbf  = (unsigned short*)(ws + alloc(8192ull * 1024 * 2));
    unsigned short* ybf   = (unsigned short*)(ws + alloc(8192ull * 1024 * 2));
    unsigned int*   scan_sum   = (unsigned int*)(ws + alloc((size_t)SCAN_NC * 8 * 16384 * 4));
    unsigned short* scan_hinit = (unsigned short*)(ws + alloc((size_t)SCAN_NC * 8 * 16384 * 2));
    unsigned short* dtpA  = (unsigned short*)(ws + alloc(8192ull * 128 * 2));
    unsigned short* dtpB  = (unsigned short*)(ws + alloc(2048ull * 128 * 2));
    unsigned short* P      = xzbf;                  // 16MB <= 32MB, dead before in_proj
    unsigned short* catbf  = dtbf;                  // 16MB == 16MB, dead before dt GEMM
    unsigned short* merged = xcbf;                  // 8MB <= 16MB, dead before conv

    // fused weight prep (cvts + dtpackB + A2 table, both layers)
    k_prep<<<6024, 256, 0, stream>>>(x, merge_w, in_proj_w, x_proj_w, out_proj_w,
                                     dt_proj_w, A_log, xbf, mw, ipw, xpw, opw, dtpB,
                                     A2tab, powflag);
    k_upT<<<dim3(16, 16, 4), dim3(32, 32), 0, stream>>>(up_w, upT);

    // stage 1: transposed-conv as GEMM (bf16 out), assemble cat, merge GEMM, LN
    k_gemm<128, 128, 1><<<dim3(16, 32), 256, 0, stream>>>(xbf, upT, nullptr, P, nullptr,
                                                          4096, 2048, 512);
    k_assemble<<<32768, 256, 0, stream>>>(P, skip, up_b, catbf);
    k_gemm<128, 128, 1><<<dim3(4, 64), 256, 0, stream>>>(catbf, mw, nullptr, merged, merge_b,
                                                         8192, 512, 1024);
    k_ln<<<2048, 256, 0, stream>>>(merged, ln_w, ln_b, ubf);

    // two mamba layers
    for (int li = 0; li < 2; ++li) {
        k_gemm<128, 128, 1><<<dim3(16, 64), 256, 0, stream>>>(ubf, ipw + (size_t)li * 2048 * 512,
                                                              nullptr, xzbf, nullptr, 8192, 2048, 512);
        k_conv<<<8192, 256, 0, stream>>>(xzbf, conv_w + li * 4096, conv_b + li * 1024, xcbf);
        // x_proj GEMM with fused dtpackA epilogue (cols<32 -> split-bf16 operand)
        k_gemm<64, 64, 4><<<dim3(1, 128), 256, 0, stream>>>(xcbf, xpw + (size_t)li * 64 * 1024,
                                                            xdbl, dtpA, nullptr, 8192, 64, 1024);
        // dt GEMM: exact split-bf16 (K=128) + fused hw-softplus -> bf16
        k_gemm<128, 64, 3><<<dim3(16, 64), 256, 0, stream>>>(dtpA, dtpB + (size_t)li * 1024 * 128,
                                                             nullptr, dtbf,
                                                             dt_proj_b + (size_t)li * 1024,
                                                             8192, 1024, 128);
        const float* A2l = A2tab + (size_t)li * 1024 * 16;
        const int*   pfl = powflag + (size_t)li * 1024;
        const float* Dl  = D_param + (size_t)li * 1024;
        k_scan_chunk<0><<<dim3(4, 8, SCAN_NC), 256, 0, stream>>>(
            dtbf, xcbf, xdbl, xzbf, A2l, pfl, Dl, scan_sum, scan_hinit, ybf);
        k_scan_carry<<<512, 256, 0, stream>>>(scan_sum, scan_hinit);
        k_scan_chunk<1><<<dim3(4, 8, SCAN_NC), 256, 0, stream>>>(
            dtbf, xcbf, xdbl, xzbf, A2l, pfl, Dl, scan_sum, scan_hinit, ybf);
        if (li == 0)
            k_gemm<128, 128, 1><<<dim3(4, 64), 256, 0, stream>>>(ybf, opw, nullptr, ubf, nullptr,
                                                                 8192, 512, 1024);
        else
            k_gemm<128, 128, 0><<<dim3(4, 64), 256, 0, stream>>>(ybf, opw + (size_t)512 * 1024,
                                                                 out, nullptr, nullptr, 8192, 512, 1024);
    }
}

// Round 26
// 404.688 us; speedup vs baseline: 1.0299x; 1.0299x over previous
//
#include <hip/hip_runtime.h>

#define DEV __device__ __forceinline__

typedef short  bf16x8 __attribute__((ext_vector_type(8)));
typedef float  f32x4  __attribute__((ext_vector_type(4)));

DEV unsigned short f2b(float f) {
    unsigned int u = __float_as_uint(f);
    u += 0x7fffu + ((u >> 16) & 1u);
    return (unsigned short)(u >> 16);
}
DEV float b2f(unsigned short h) { return __uint_as_float((unsigned int)h << 16); }
DEV float silu(float x) { return x / (1.f + __expf(-x)); }
DEV float fexp2(float x) { return __builtin_amdgcn_exp2f(x); }   // raw v_exp_f32
DEV float flog2(float x) { return __builtin_amdgcn_logf(x); }    // raw v_log_f32

// async global->LDS, 16B per lane: HW writes lane l at ldsbase + l*16
typedef const __attribute__((address_space(1))) unsigned int GU32;
typedef __attribute__((address_space(3))) unsigned int LU32;
DEV void gload16(const unsigned short* g, unsigned short* l) {
    __builtin_amdgcn_global_load_lds((GU32*)g, (LU32*)l, 16, 0, 0);
}

// ---------------------------------------------------------------------------
// fused prep: weight f32->bf16 conversions + dt_proj_w split-bf16 packing +
// scan A2 table (-exp(A_log)*log2e) with integer-power flag.
__global__ __launch_bounds__(256) void k_prep(
        const float* __restrict__ x, const float* __restrict__ merge_w,
        const float* __restrict__ in_proj_w, const float* __restrict__ x_proj_w,
        const float* __restrict__ out_proj_w, const float* __restrict__ dt_proj_w,
        const float* __restrict__ A_log,
        unsigned short* __restrict__ xbf, unsigned short* __restrict__ mw,
        unsigned short* __restrict__ ipw, unsigned short* __restrict__ xpw,
        unsigned short* __restrict__ opw, unsigned short* __restrict__ dtpB,
        float* __restrict__ A2tab, int* __restrict__ powflag) {
    size_t i = (size_t)blockIdx.x * 256 + threadIdx.x;
    const size_t n0 = 524288;           // x: 4096*512/4
    const size_t n1 = n0 + 131072;      // merge_w: 512*1024/4
    const size_t n2 = n1 + 524288;      // in_proj: 2*2048*512/4
    const size_t n3 = n2 + 32768;       // x_proj: 2*64*1024/4
    const size_t n4 = n3 + 262144;      // out_proj: 2*512*1024/4
    const size_t n5 = n4 + 65536;       // dtpackB: 2*1024*32 scalars
    const size_t n6 = n5 + 2048;        // A2 table: one thread per d (2 layers)
    if (i < n4) {
        const float* s; unsigned short* d; size_t j;
        if (i < n0)      { s = x;          d = xbf; j = i; }
        else if (i < n1) { s = merge_w;    d = mw;  j = i - n0; }
        else if (i < n2) { s = in_proj_w;  d = ipw; j = i - n1; }
        else if (i < n3) { s = x_proj_w;   d = xpw; j = i - n2; }
        else             { s = out_proj_w; d = opw; j = i - n3; }
        float4 v = *(const float4*)(s + j * 4);
        ushort4 o = { f2b(v.x), f2b(v.y), f2b(v.z), f2b(v.w) };
        *(ushort4*)(d + j * 4) = o;
    } else if (i < n5) {
        size_t j = i - n4;              // (li*1024+d)*32 + r
        int r = (int)(j & 31);
        size_t dg = j >> 5;             // global d in [0, 2048)
        float xw = dt_proj_w[dg * 32 + r];
        unsigned short wh = f2b(xw);
        unsigned short wl = f2b(xw - b2f(wh));
        size_t base = dg * 128;
        dtpB[base + r]      = wh;
        dtpB[base + 32 + r] = wl;
        dtpB[base + 64 + r] = wl;
        dtpB[base + 96 + r] = wh;
    } else if (i < n6) {
        size_t dg = i - n5;             // [0, 2048)
        constexpr float LOG2E = 1.4426950408889634f;
        float a2[16];
#pragma unroll
        for (int s = 0; s < 16; ++s)
            a2[s] = -expf(A_log[dg * 16 + s]) * LOG2E;
        bool ok = true;
#pragma unroll
        for (int s = 1; s < 16; ++s)
            ok = ok && (fabsf(a2[s] - (float)(s + 1) * a2[0]) <= 1e-5f * fabsf(a2[s]));
#pragma unroll
        for (int s = 0; s < 16; s += 4)
            *(f32x4*)(A2tab + dg * 16 + s) = *(const f32x4*)&a2[s];
        powflag[dg] = ok ? 1 : 0;
    }
}

// up_w (512 x 512 x 4) [i,o,k] -> upT[(k*512+o)*512 + i] bf16
__global__ void k_upT(const float* __restrict__ up_w, unsigned short* __restrict__ upT) {
    __shared__ float t[32][33];
    int tx = threadIdx.x, ty = threadIdx.y;
    int o0 = blockIdx.x * 32, i0 = blockIdx.y * 32, kz = blockIdx.z;
    t[ty][tx] = up_w[(size_t)(i0 + ty) * 2048 + (o0 + tx) * 4 + kz];
    __syncthreads();
    upT[(size_t)(kz * 512 + o0 + ty) * 512 + i0 + tx] = f2b(t[tx][ty]);
}

// ---------------------------------------------------------------------------
// bf16 MFMA GEMM, NT: C[m,n] = sum_k A[m,k]*B[n,k].  BK=64, 4 waves,
// global_load_lds staging with T2 XOR-swizzle (rule #21: linear LDS dest +
// inverse-swizzled GLOBAL source + swizzled READ).
// XCD-aware block swizzle (T1): contiguous tile chunks per XCD for L2 reuse.
// Tiles: (BM,BN) in {(128,128),(128,64),(64,64)}.
// OUTMODE 0: f32 out, 1: bf16 out, 2: softplus->f32, 3: softplus->bf16,
//         4: f32 out + dtpackA for cols<32 (split-bf16 K=128 operand).
template <int BM, int BN, int OUTMODE>
__global__ __launch_bounds__(256) void k_gemm(const unsigned short* __restrict__ A,
                                              const unsigned short* __restrict__ B,
                                              float* __restrict__ Cf,
                                              unsigned short* __restrict__ Cb,
                                              const float* __restrict__ bias,
                                              int M, int N, int K) {
    constexpr int BK = 64;
    constexpr int WM = (BN == 128) ? 64 : 32;
    constexpr int WN = (BM == 64 && BN == 64) ? 32 : 64;
    constexpr int MI = WM / 16, NI = WN / 16;
    __shared__ unsigned short As[BM * BK];
    __shared__ unsigned short Bs[BN * BK];
    const int tid = threadIdx.x;
    const int wid = tid >> 6, lane = tid & 63;

    // XCD swizzle: hw bids round-robin XCDs; map same-XCD bids to contiguous tiles
    int bid = blockIdx.y * gridDim.x + blockIdx.x;
    const int nwg = gridDim.x * gridDim.y;
    if ((nwg & 7) == 0) {
        int cpx = nwg >> 3;
        bid = (bid & 7) * cpx + (bid >> 3);
    }
    const int bx = bid % gridDim.x, by = bid / gridDim.x;
    const int m0 = by * BM, n0 = bx * BN;

    int wr, wc;
    if (BN == 128)      { wr = wid >> 1; wc = wid & 1; }
    else if (BM == 128) { wr = wid;      wc = 0;       }
    else                { wr = wid & 1;  wc = wid >> 1; }
    const int wm0 = wr * WM, wn0 = wc * WN;
    const int fr = lane & 15, fh = lane >> 4;

    // staging (BK=64): one gload16 covers 8 rows; lane l -> row (l>>3).
    // Global source col chunk pre-swizzled: chunk = (l&7) ^ (l>>3), because
    // staged rows step by 32 so (row & 7) == (l>>3) for this lane always.
    const int srow = lane >> 3;
    const int scol = (((lane & 7) ^ srow)) * 8;
    const unsigned short* Ag = A + (size_t)(m0 + wid * 8 + srow) * K + scol;
    const unsigned short* Bg = B + (size_t)(n0 + wid * 8 + srow) * K + scol;
    unsigned short* AsB = &As[wid * 8 * BK];
    unsigned short* BsB = &Bs[wid * 8 * BK];

    f32x4 acc[MI][NI];
#pragma unroll
    for (int i = 0; i < MI; ++i)
#pragma unroll
        for (int j = 0; j < NI; ++j) acc[i][j] = (f32x4){0.f, 0.f, 0.f, 0.f};

    const int frx = fr & 7;   // read-side XOR factor (row & 7)
    for (int k0 = 0; k0 < K; k0 += BK) {
#pragma unroll
        for (int i = 0; i < BM / 32; ++i)
            gload16(Ag + (size_t)(i * 32) * K + k0, AsB + i * 32 * BK);
#pragma unroll
        for (int i = 0; i < BN / 32; ++i)
            gload16(Bg + (size_t)(i * 32) * K + k0, BsB + i * 32 * BK);
        __syncthreads();
#pragma unroll
        for (int kk = 0; kk < BK; kk += 32) {
            bf16x8 av[MI], bv[NI];
#pragma unroll
            for (int mi = 0; mi < MI; ++mi)
                av[mi] = *(const bf16x8*)(&As[(wm0 + mi * 16 + fr) * BK +
                                              ((((kk >> 3) + fh) ^ frx) << 3)]);
#pragma unroll
            for (int ni = 0; ni < NI; ++ni)
                bv[ni] = *(const bf16x8*)(&Bs[(wn0 + ni * 16 + fr) * BK +
                                              ((((kk >> 3) + fh) ^ frx) << 3)]);
#pragma unroll
            for (int mi = 0; mi < MI; ++mi)
#pragma unroll
                for (int ni = 0; ni < NI; ++ni)
                    acc[mi][ni] = __builtin_amdgcn_mfma_f32_16x16x32_bf16(av[mi], bv[ni],
                                                                          acc[mi][ni], 0, 0, 0);
        }
        __syncthreads();
    }
    constexpr float LOG2E = 1.4426950408889634f;
    constexpr float LN2   = 0.6931471805599453f;
#pragma unroll
    for (int mi = 0; mi < MI; ++mi) {
#pragma unroll
        for (int ni = 0; ni < NI; ++ni) {
            int col = n0 + wn0 + ni * 16 + fr;
            float bb = bias ? bias[col] : 0.f;
#pragma unroll
            for (int j = 0; j < 4; ++j) {
                int row = m0 + wm0 + mi * 16 + fh * 4 + j;
                float v = acc[mi][ni][j] + bb;
                if (OUTMODE == 0)      Cf[(size_t)row * N + col] = v;
                else if (OUTMODE == 1) Cb[(size_t)row * N + col] = f2b(v);
                else if (OUTMODE == 4) {
                    Cf[(size_t)row * N + col] = v;
                    if (col < 32) {
                        unsigned short xh = f2b(v);
                        unsigned short xl = f2b(v - b2f(xh));
                        size_t base = (size_t)row * 128;
                        Cb[base + col]      = xh;
                        Cb[base + 32 + col] = xl;
                        Cb[base + 64 + col] = xh;
                        Cb[base + 96 + col] = xl;
                    }
                } else {
                    float sp = (v > 20.f) ? v : flog2(1.f + fexp2(v * LOG2E)) * LN2;
                    if (OUTMODE == 2) Cf[(size_t)row * N + col] = sp;
                    else              Cb[(size_t)row * N + col] = f2b(sp);
                }
            }
        }
    }
}

// ---------------------------------------------------------------------------
// assemble cat row-major (8192 x 1024) bf16: [0,512)=xu from P(bf16), rest=skip
__global__ __launch_bounds__(256) void k_assemble(const unsigned short* __restrict__ P,
                                                  const float* __restrict__ skip,
                                                  const float* __restrict__ up_b,
                                                  unsigned short* __restrict__ catbf) {
    int bx = blockIdx.x;
    int m = bx >> 2;
    int c = (bx & 3) * 256 + threadIdx.x;
    int b = m >> 10, t = m & 1023, j = t >> 1;
    float v;
    if (c < 512) {
        size_t rb = (size_t)((b << 9) + j) * 2048;
        if (t & 1) {                       // odd t: k=2 @ j, k=0 @ j+1
            v = b2f(P[rb + 1024 + c]);
            if (j + 1 < 512) v += b2f(P[rb + 2048 + c]);
        } else {                           // even t: k=3 @ j-1, k=1 @ j
            v = b2f(P[rb + 512 + c]);
            if (j >= 1) v += b2f(P[rb - 2048 + 1536 + c]);
        }
        v += up_b[c];
    } else {
        v = skip[(size_t)m * 512 + (c - 512)];
    }
    catbf[(size_t)m * 1024 + c] = f2b(v);
}

// LayerNorm over 512 (bf16 input), 4 rows per 256-block, writes bf16
__global__ __launch_bounds__(256) void k_ln(const unsigned short* __restrict__ merged,
                                            const float* __restrict__ w,
                                            const float* __restrict__ bvec,
                                            unsigned short* __restrict__ outb) {
    int row = blockIdx.x * 4 + (threadIdx.x >> 6);
    int lane = threadIdx.x & 63;
    const unsigned short* r = merged + (size_t)row * 512 + lane * 8;
    bf16x8 v = *(const bf16x8*)r;
    float xv[8];
#pragma unroll
    for (int e = 0; e < 8; ++e) xv[e] = b2f((unsigned short)v[e]);
    float s = 0.f, ss = 0.f;
#pragma unroll
    for (int e = 0; e < 8; ++e) { s += xv[e]; ss += xv[e] * xv[e]; }
#pragma unroll
    for (int m = 1; m < 64; m <<= 1) { s += __shfl_xor(s, m, 64); ss += __shfl_xor(ss, m, 64); }
    float mean = s * (1.f / 512.f);
    float var = ss * (1.f / 512.f) - mean * mean;
    float inv = rsqrtf(var + 1e-5f);
    unsigned short o8[8];
#pragma unroll
    for (int e = 0; e < 8; ++e) {
        int c = lane * 8 + e;
        o8[e] = f2b((xv[e] - mean) * inv * w[c] + bvec[c]);
    }
    *(int4*)(outb + (size_t)row * 512 + lane * 8) = *(const int4*)o8;
}

// causal depthwise conv K=4 + bias + silu; 4 channels/thread, bf16 in/out
__global__ __launch_bounds__(256) void k_conv(const unsigned short* __restrict__ xzb,
                                              const float* __restrict__ cw,
                                              const float* __restrict__ cb,
                                              unsigned short* __restrict__ xcb) {
    int i = blockIdx.x * 256 + threadIdx.x;   // 2.1M threads
    int m = i >> 8;
    int c0 = (i & 255) * 4;
    int l = m & 1023;
    float4 w0 = *(const float4*)(cw + (size_t)(c0 + 0) * 4);
    float4 w1 = *(const float4*)(cw + (size_t)(c0 + 1) * 4);
    float4 w2 = *(const float4*)(cw + (size_t)(c0 + 2) * 4);
    float4 w3 = *(const float4*)(cw + (size_t)(c0 + 3) * 4);
    float4 acc = *(const float4*)(cb + c0);
    const float* wp0 = (const float*)&w0;
    const float* wp1 = (const float*)&w1;
    const float* wp2 = (const float*)&w2;
    const float* wp3 = (const float*)&w3;
#pragma unroll
    for (int k = 0; k < 4; ++k) {
        int lp = l - 3 + k;
        if (lp >= 0) {
            ushort4 xv = *(const ushort4*)(xzb + (size_t)(m - l + lp) * 2048 + c0);
            acc.x = fmaf(wp0[k], b2f(xv.x), acc.x);
            acc.y = fmaf(wp1[k], b2f(xv.y), acc.y);
            acc.z = fmaf(wp2[k], b2f(xv.z), acc.z);
            acc.w = fmaf(wp3[k], b2f(xv.w), acc.w);
        }
    }
    ushort4 o = { f2b(silu(acc.x)), f2b(silu(acc.y)), f2b(silu(acc.z)), f2b(silu(acc.w)) };
    *(ushort4*)(xcb + (size_t)m * 1024 + c0) = o;
}

// ---------------------------------------------------------------------------
// Chunked selective scan.  L=1024 split into NC=32 chunks of CL=32.
// Thread = (b, d, chunk), 16 states in registers.  dt/u staged in LDS;
// A2 row + power flag loaded from precomputed table (k_prep).
// Power fast path: chain form a *= a1 (compiler pipelines it best; tree
// variant measured SLOWER in round 25).
// Summaries COMPRESSED: phase0 stores packed uint32 (bf16 a | bf16 h << 16);
// carry writes compact bf16 h_init; phase1 reads bf16 h_init.
constexpr int SCAN_NC = 32;
constexpr int SCAN_CL = 32;

template <int PHASE>
__global__ __launch_bounds__(256) void k_scan_chunk(
        const unsigned short* __restrict__ dtb, const unsigned short* __restrict__ xcb,
        const float* __restrict__ xdbl, const unsigned short* __restrict__ xzb,
        const float* __restrict__ A2tab, const int* __restrict__ powflag,
        const float* __restrict__ Dp,
        unsigned int* __restrict__ sum, const unsigned short* __restrict__ hinit,
        unsigned short* __restrict__ ybf) {
    constexpr int CL = SCAN_CL;
    const int tid = threadIdx.x;
    const int d0 = blockIdx.x * 256;
    const int d = d0 + tid;
    const int b = blockIdx.y, c = blockIdx.z;
    const size_t mbase = (size_t)b * 1024 + (size_t)c * CL;

    // bulk-stage chunk inputs into LDS (coalesced 16B chunks, all in flight):
    //   sBC: B/C slice of xdbl; sdt/su: this block's dt/u [CL][256] bf16.
    __shared__ float sBC[CL][32];
    __shared__ unsigned short sdt[CL][256];
    __shared__ unsigned short su[CL][256];
    {
        int row = tid >> 3, q = tid & 7;   // CL*8 == 256
        *(float4*)&sBC[row][q * 4] =
            *(const float4*)(xdbl + (mbase + row) * 64 + 32 + q * 4);
    }
    for (int i = tid; i < CL * 32; i += 256) {       // 32 rows x 32 16B-chunks
        int row = i >> 5, q = i & 31;
        const size_t g = (mbase + row) * 1024 + d0 + q * 8;
        *(int4*)&sdt[row][q * 8] = *(const int4*)(dtb + g);
        *(int4*)&su[row][q * 8]  = *(const int4*)(xcb + g);
    }
    __syncthreads();

    float A2[16], h[16];
#pragma unroll
    for (int s = 0; s < 16; s += 4)
        *(f32x4*)&A2[s] = *(const f32x4*)(A2tab + (size_t)d * 16 + s);
    const bool powok = powflag[d] != 0;

    const size_t sumbase = ((size_t)(b * SCAN_NC + c) << 14) + d * 16;
    if (PHASE == 0) {
#pragma unroll
        for (int s = 0; s < 16; ++s) h[s] = 0.f;
    } else {
#pragma unroll
        for (int s = 0; s < 16; s += 8) {
            bf16x8 hv = *(const bf16x8*)(hinit + sumbase + s);
#pragma unroll
            for (int j = 0; j < 8; ++j) h[s + j] = b2f((unsigned short)hv[j]);
        }
    }
    float dtsum = 0.f;
    const float Dv = (PHASE == 1) ? Dp[d] : 0.f;

    // z prefetch one step ahead (phase 1 only)
    float zv_n = 0.f;
    if (PHASE == 1) zv_n = b2f(xzb[mbase * 2048 + 1024 + d]);

#pragma unroll 2
    for (int l = 0; l < CL; ++l) {
        const size_t m = mbase + l;
        const float dtv_c = b2f(sdt[l][tid]);
        const float uv_c  = b2f(su[l][tid]);
        float zv;
        if (PHASE == 1) {
            zv = zv_n;
            if (l + 1 < CL) zv_n = b2f(xzb[(m + 1) * 2048 + 1024 + d]);
        }
        const float dtu = dtv_c * uv_c;
        if (PHASE == 0) dtsum += dtv_c;
        float Bv[16], Cv[16];
#pragma unroll
        for (int q = 0; q < 4; ++q) {
            *(float4*)&Bv[q * 4] = *(const float4*)&sBC[l][q * 4];
            if (PHASE == 1)
                *(float4*)&Cv[q * 4] = *(const float4*)&sBC[l][16 + q * 4];
        }
        float p = 0.f;
        if (powok) {
            const float a1 = fexp2(dtv_c * A2[0]);
            float a = a1;
#pragma unroll
            for (int s = 0; s < 16; ++s) {
                h[s] = fmaf(a, h[s], dtu * Bv[s]);
                if (PHASE == 1) p = fmaf(h[s], Cv[s], p);
                a *= a1;
            }
        } else {
#pragma unroll
            for (int s = 0; s < 16; ++s) {
                float a = fexp2(dtv_c * A2[s]);
                h[s] = fmaf(a, h[s], dtu * Bv[s]);
                if (PHASE == 1) p = fmaf(h[s], Cv[s], p);
            }
        }
        if (PHASE == 1) {
            ybf[m * 1024 + d] = f2b((p + Dv * uv_c) * silu(zv));
        }
    }
    if (PHASE == 0) {
        float aprod[16];
        if (powok) {
            const float ap1 = fexp2(A2[0] * dtsum);
            float a = ap1;
#pragma unroll
            for (int s = 0; s < 16; ++s) { aprod[s] = a; a *= ap1; }
        } else {
#pragma unroll
            for (int s = 0; s < 16; ++s) aprod[s] = fexp2(A2[s] * dtsum);
        }
        unsigned int pk[16];
#pragma unroll
        for (int s = 0; s < 16; ++s)
            pk[s] = (unsigned int)f2b(aprod[s]) | ((unsigned int)f2b(h[s]) << 16);
#pragma unroll
        for (int s = 0; s < 16; s += 4)
            *(uint4*)(sum + sumbase + s) = *(const uint4*)&pk[s];
    }
}

// carry scan over packed chunk summaries; writes compact bf16 h_init.
__global__ __launch_bounds__(256) void k_scan_carry(const unsigned int* __restrict__ sum,
                                                    unsigned short* __restrict__ hinit) {
    int i = blockIdx.x * 256 + threadIdx.x;   // (b, d*16+s)
    int b = i >> 14, ds = i & 16383;
    float h = 0.f;
    for (int c = 0; c < SCAN_NC; ++c) {
        size_t idx = ((size_t)(b * SCAN_NC + c) << 14) + ds;
        unsigned int u = sum[idx];
        float a = b2f((unsigned short)(u & 0xffffu));
        float f = b2f((unsigned short)(u >> 16));
        hinit[idx] = f2b(h);
        h = fmaf(a, h, f);
    }
}

// ---------------------------------------------------------------------------
extern "C" void kernel_launch(void* const* d_in, const int* in_sizes, int n_in,
                              void* d_out, int out_size, void* d_ws, size_t ws_size,
                              hipStream_t stream) {
    const float* x         = (const float*)d_in[0];
    const float* skip      = (const float*)d_in[1];
    const float* up_w      = (const float*)d_in[2];
    const float* up_b      = (const float*)d_in[3];
    const float* merge_w   = (const float*)d_in[4];
    const float* merge_b   = (const float*)d_in[5];
    const float* ln_w      = (const float*)d_in[6];
    const float* ln_b      = (const float*)d_in[7];
    const float* in_proj_w = (const float*)d_in[8];
    const float* conv_w    = (const float*)d_in[9];
    const float* conv_b    = (const float*)d_in[10];
    const float* x_proj_w  = (const float*)d_in[11];
    const float* dt_proj_w = (const float*)d_in[12];
    const float* dt_proj_b = (const float*)d_in[13];
    const float* A_log     = (const float*)d_in[14];
    const float* D_param   = (const float*)d_in[15];
    const float* out_proj_w= (const float*)d_in[16];
    float* out = (float*)d_out;

    char* ws = (char*)d_ws;
    size_t off = 0;
    auto alloc = [&](size_t bytes) { size_t r = off; off += (bytes + 255) & ~(size_t)255; return r; };

    // persistent
    unsigned short* upT  = (unsigned short*)(ws + alloc(2048ull * 512 * 2));
    unsigned short* mw   = (unsigned short*)(ws + alloc(512ull * 1024 * 2));
    unsigned short* ipw  = (unsigned short*)(ws + alloc(2ull * 2048 * 512 * 2));
    unsigned short* xpw  = (unsigned short*)(ws + alloc(2ull * 64 * 1024 * 2));
    unsigned short* opw  = (unsigned short*)(ws + alloc(2ull * 512 * 1024 * 2));
    unsigned short* xbf  = (unsigned short*)(ws + alloc(4096ull * 512 * 2));
    unsigned short* ubf  = (unsigned short*)(ws + alloc(8192ull * 512 * 2));
    float*          A2tab   = (float*)(ws + alloc(2048ull * 16 * 4));
    int*            powflag = (int*)(ws + alloc(2048ull * 4));
    // per-layer arena (stage-1 buffers aliased in)
    unsigned short* xzbf  = (unsigned short*)(ws + alloc(8192ull * 2048 * 2));
    unsigned short* xcbf  = (unsigned short*)(ws + alloc(8192ull * 1024 * 2));
    float*          xdbl  = (float*)(ws + alloc(8192ull * 64 * 4));
    unsigned short* dtbf  = (unsigned short*)(ws + alloc(8192ull * 1024 * 2));
    unsigned short* ybf   = (unsigned short*)(ws + alloc(8192ull * 1024 * 2));
    unsigned int*   scan_sum   = (unsigned int*)(ws + alloc((size_t)SCAN_NC * 8 * 16384 * 4));
    unsigned short* scan_hinit = (unsigned short*)(ws + alloc((size_t)SCAN_NC * 8 * 16384 * 2));
    unsigned short* dtpA  = (unsigned short*)(ws + alloc(8192ull * 128 * 2));
    unsigned short* dtpB  = (unsigned short*)(ws + alloc(2048ull * 128 * 2));
    unsigned short* P      = xzbf;                  // 16MB <= 32MB, dead before in_proj
    unsigned short* catbf  = dtbf;                  // 16MB == 16MB, dead before dt GEMM
    unsigned short* merged = xcbf;                  // 8MB <= 16MB, dead before conv

    // fused weight prep (cvts + dtpackB + A2 table, both layers)
    k_prep<<<6024, 256, 0, stream>>>(x, merge_w, in_proj_w, x_proj_w, out_proj_w,
                                     dt_proj_w, A_log, xbf, mw, ipw, xpw, opw, dtpB,
                                     A2tab, powflag);
    k_upT<<<dim3(16, 16, 4), dim3(32, 32), 0, stream>>>(up_w, upT);

    // stage 1: transposed-conv as GEMM (bf16 out), assemble cat, merge GEMM, LN
    k_gemm<128, 128, 1><<<dim3(16, 32), 256, 0, stream>>>(xbf, upT, nullptr, P, nullptr,
                                                          4096, 2048, 512);
    k_assemble<<<32768, 256, 0, stream>>>(P, skip, up_b, catbf);
    k_gemm<128, 128, 1><<<dim3(4, 64), 256, 0, stream>>>(catbf, mw, nullptr, merged, merge_b,
                                                         8192, 512, 1024);
    k_ln<<<2048, 256, 0, stream>>>(merged, ln_w, ln_b, ubf);

    // two mamba layers
    for (int li = 0; li < 2; ++li) {
        k_gemm<128, 128, 1><<<dim3(16, 64), 256, 0, stream>>>(ubf, ipw + (size_t)li * 2048 * 512,
                                                              nullptr, xzbf, nullptr, 8192, 2048, 512);
        k_conv<<<8192, 256, 0, stream>>>(xzbf, conv_w + li * 4096, conv_b + li * 1024, xcbf);
        // x_proj GEMM with fused dtpackA epilogue (cols<32 -> split-bf16 operand)
        k_gemm<64, 64, 4><<<dim3(1, 128), 256, 0, stream>>>(xcbf, xpw + (size_t)li * 64 * 1024,
                                                            xdbl, dtpA, nullptr, 8192, 64, 1024);
        // dt GEMM: exact split-bf16 (K=128) + fused hw-softplus -> bf16
        k_gemm<128, 64, 3><<<dim3(16, 64), 256, 0, stream>>>(dtpA, dtpB + (size_t)li * 1024 * 128,
                                                             nullptr, dtbf,
                                                             dt_proj_b + (size_t)li * 1024,
                                                             8192, 1024, 128);
        const float* A2l = A2tab + (size_t)li * 1024 * 16;
        const int*   pfl = powflag + (size_t)li * 1024;
        const float* Dl  = D_param + (size_t)li * 1024;
        k_scan_chunk<0><<<dim3(4, 8, SCAN_NC), 256, 0, stream>>>(
            dtbf, xcbf, xdbl, xzbf, A2l, pfl, Dl, scan_sum, scan_hinit, ybf);
        k_scan_carry<<<512, 256, 0, stream>>>(scan_sum, scan_hinit);
        k_scan_chunk<1><<<dim3(4, 8, SCAN_NC), 256, 0, stream>>>(
            dtbf, xcbf, xdbl, xzbf, A2l, pfl, Dl, scan_sum, scan_hinit, ybf);
        if (li == 0)
            k_gemm<128, 128, 1><<<dim3(4, 64), 256, 0, stream>>>(ybf, opw, nullptr, ubf, nullptr,
                                                                 8192, 512, 1024);
        else
            k_gemm<128, 128, 0><<<dim3(4, 64), 256, 0, stream>>>(ybf, opw + (size_t)512 * 1024,
                                                                 out, nullptr, nullptr, 8192, 512, 1024);
    }
}

// Round 28
// 404.318 us; speedup vs baseline: 1.0308x; 1.0009x over previous
//
#include <hip/hip_runtime.h>

#define DEV __device__ __forceinline__

typedef short  bf16x8 __attribute__((ext_vector_type(8)));
typedef float  f32x4  __attribute__((ext_vector_type(4)));

DEV unsigned short f2b(float f) {
    unsigned int u = __float_as_uint(f);
    u += 0x7fffu + ((u >> 16) & 1u);
    return (unsigned short)(u >> 16);
}
DEV float b2f(unsigned short h) { return __uint_as_float((unsigned int)h << 16); }
DEV float silu(float x) { return x / (1.f + __expf(-x)); }
DEV float fexp2(float x) { return __builtin_amdgcn_exp2f(x); }   // raw v_exp_f32
DEV float flog2(float x) { return __builtin_amdgcn_logf(x); }    // raw v_log_f32

// async global->LDS, 16B per lane: HW writes lane l at ldsbase + l*16
typedef const __attribute__((address_space(1))) unsigned int GU32;
typedef __attribute__((address_space(3))) unsigned int LU32;
DEV void gload16(const unsigned short* g, unsigned short* l) {
    __builtin_amdgcn_global_load_lds((GU32*)g, (LU32*)l, 16, 0, 0);
}

// ---------------------------------------------------------------------------
// fused prep: weight f32->bf16 conversions + dt_proj_w split-bf16 packing +
// scan A2 table (-exp(A_log)*log2e) with integer-power flag.
__global__ __launch_bounds__(256) void k_prep(
        const float* __restrict__ x, const float* __restrict__ merge_w,
        const float* __restrict__ in_proj_w, const float* __restrict__ x_proj_w,
        const float* __restrict__ out_proj_w, const float* __restrict__ dt_proj_w,
        const float* __restrict__ A_log,
        unsigned short* __restrict__ xbf, unsigned short* __restrict__ mw,
        unsigned short* __restrict__ ipw, unsigned short* __restrict__ xpw,
        unsigned short* __restrict__ opw, unsigned short* __restrict__ dtpB,
        float* __restrict__ A2tab, int* __restrict__ powflag) {
    size_t i = (size_t)blockIdx.x * 256 + threadIdx.x;
    const size_t n0 = 524288;           // x: 4096*512/4
    const size_t n1 = n0 + 131072;      // merge_w: 512*1024/4
    const size_t n2 = n1 + 524288;      // in_proj: 2*2048*512/4
    const size_t n3 = n2 + 32768;       // x_proj: 2*64*1024/4
    const size_t n4 = n3 + 262144;      // out_proj: 2*512*1024/4
    const size_t n5 = n4 + 65536;       // dtpackB: 2*1024*32 scalars
    const size_t n6 = n5 + 2048;        // A2 table: one thread per d (2 layers)
    if (i < n4) {
        const float* s; unsigned short* d; size_t j;
        if (i < n0)      { s = x;          d = xbf; j = i; }
        else if (i < n1) { s = merge_w;    d = mw;  j = i - n0; }
        else if (i < n2) { s = in_proj_w;  d = ipw; j = i - n1; }
        else if (i < n3) { s = x_proj_w;   d = xpw; j = i - n2; }
        else             { s = out_proj_w; d = opw; j = i - n3; }
        float4 v = *(const float4*)(s + j * 4);
        ushort4 o = { f2b(v.x), f2b(v.y), f2b(v.z), f2b(v.w) };
        *(ushort4*)(d + j * 4) = o;
    } else if (i < n5) {
        size_t j = i - n4;              // (li*1024+d)*32 + r
        int r = (int)(j & 31);
        size_t dg = j >> 5;             // global d in [0, 2048)
        float xw = dt_proj_w[dg * 32 + r];
        unsigned short wh = f2b(xw);
        unsigned short wl = f2b(xw - b2f(wh));
        size_t base = dg * 128;
        dtpB[base + r]      = wh;
        dtpB[base + 32 + r] = wl;
        dtpB[base + 64 + r] = wl;
        dtpB[base + 96 + r] = wh;
    } else if (i < n6) {
        size_t dg = i - n5;             // [0, 2048)
        constexpr float LOG2E = 1.4426950408889634f;
        float a2[16];
#pragma unroll
        for (int s = 0; s < 16; ++s)
            a2[s] = -expf(A_log[dg * 16 + s]) * LOG2E;
        bool ok = true;
#pragma unroll
        for (int s = 1; s < 16; ++s)
            ok = ok && (fabsf(a2[s] - (float)(s + 1) * a2[0]) <= 1e-5f * fabsf(a2[s]));
#pragma unroll
        for (int s = 0; s < 16; s += 4)
            *(f32x4*)(A2tab + dg * 16 + s) = *(const f32x4*)&a2[s];
        powflag[dg] = ok ? 1 : 0;
    }
}

// up_w (512 x 512 x 4) [i,o,k] -> upT[(k*512+o)*512 + i] bf16
__global__ void k_upT(const float* __restrict__ up_w, unsigned short* __restrict__ upT) {
    __shared__ float t[32][33];
    int tx = threadIdx.x, ty = threadIdx.y;
    int o0 = blockIdx.x * 32, i0 = blockIdx.y * 32, kz = blockIdx.z;
    t[ty][tx] = up_w[(size_t)(i0 + ty) * 2048 + (o0 + tx) * 4 + kz];
    __syncthreads();
    upT[(size_t)(kz * 512 + o0 + ty) * 512 + i0 + tx] = f2b(t[tx][ty]);
}

// ---------------------------------------------------------------------------
// bf16 MFMA GEMM, NT: C[m,n] = sum_k A[m,k]*B[n,k].  BK=64, 4 waves,
// global_load_lds staging with T2 XOR-swizzle (rule #21: linear LDS dest +
// inverse-swizzled GLOBAL source + swizzled READ).
// XCD-aware block swizzle (T1): contiguous tile chunks per XCD for L2 reuse.
// Tiles: (BM,BN) in {(128,128),(128,64),(64,64)}.
// OUTMODE 0: f32 out, 1: bf16 out, 2: softplus->f32, 3: softplus->bf16,
//         4: f32 out + dtpackA for cols<32 (split-bf16 K=128 operand).
template <int BM, int BN, int OUTMODE>
__global__ __launch_bounds__(256) void k_gemm(const unsigned short* __restrict__ A,
                                              const unsigned short* __restrict__ B,
                                              float* __restrict__ Cf,
                                              unsigned short* __restrict__ Cb,
                                              const float* __restrict__ bias,
                                              int M, int N, int K) {
    constexpr int BK = 64;
    constexpr int WM = (BN == 128) ? 64 : 32;
    constexpr int WN = (BM == 64 && BN == 64) ? 32 : 64;
    constexpr int MI = WM / 16, NI = WN / 16;
    __shared__ unsigned short As[BM * BK];
    __shared__ unsigned short Bs[BN * BK];
    const int tid = threadIdx.x;
    const int wid = tid >> 6, lane = tid & 63;

    // XCD swizzle: hw bids round-robin XCDs; map same-XCD bids to contiguous tiles
    int bid = blockIdx.y * gridDim.x + blockIdx.x;
    const int nwg = gridDim.x * gridDim.y;
    if ((nwg & 7) == 0) {
        int cpx = nwg >> 3;
        bid = (bid & 7) * cpx + (bid >> 3);
    }
    const int bx = bid % gridDim.x, by = bid / gridDim.x;
    const int m0 = by * BM, n0 = bx * BN;

    int wr, wc;
    if (BN == 128)      { wr = wid >> 1; wc = wid & 1; }
    else if (BM == 128) { wr = wid;      wc = 0;       }
    else                { wr = wid & 1;  wc = wid >> 1; }
    const int wm0 = wr * WM, wn0 = wc * WN;
    const int fr = lane & 15, fh = lane >> 4;

    // staging (BK=64): one gload16 covers 8 rows; lane l -> row (l>>3).
    // Global source col chunk pre-swizzled: chunk = (l&7) ^ (l>>3), because
    // staged rows step by 32 so (row & 7) == (l>>3) for this lane always.
    const int srow = lane >> 3;
    const int scol = (((lane & 7) ^ srow)) * 8;
    const unsigned short* Ag = A + (size_t)(m0 + wid * 8 + srow) * K + scol;
    const unsigned short* Bg = B + (size_t)(n0 + wid * 8 + srow) * K + scol;
    unsigned short* AsB = &As[wid * 8 * BK];
    unsigned short* BsB = &Bs[wid * 8 * BK];

    f32x4 acc[MI][NI];
#pragma unroll
    for (int i = 0; i < MI; ++i)
#pragma unroll
        for (int j = 0; j < NI; ++j) acc[i][j] = (f32x4){0.f, 0.f, 0.f, 0.f};

    const int frx = fr & 7;   // read-side XOR factor (row & 7)
    for (int k0 = 0; k0 < K; k0 += BK) {
#pragma unroll
        for (int i = 0; i < BM / 32; ++i)
            gload16(Ag + (size_t)(i * 32) * K + k0, AsB + i * 32 * BK);
#pragma unroll
        for (int i = 0; i < BN / 32; ++i)
            gload16(Bg + (size_t)(i * 32) * K + k0, BsB + i * 32 * BK);
        __syncthreads();
#pragma unroll
        for (int kk = 0; kk < BK; kk += 32) {
            bf16x8 av[MI], bv[NI];
#pragma unroll
            for (int mi = 0; mi < MI; ++mi)
                av[mi] = *(const bf16x8*)(&As[(wm0 + mi * 16 + fr) * BK +
                                              ((((kk >> 3) + fh) ^ frx) << 3)]);
#pragma unroll
            for (int ni = 0; ni < NI; ++ni)
                bv[ni] = *(const bf16x8*)(&Bs[(wn0 + ni * 16 + fr) * BK +
                                              ((((kk >> 3) + fh) ^ frx) << 3)]);
#pragma unroll
            for (int mi = 0; mi < MI; ++mi)
#pragma unroll
                for (int ni = 0; ni < NI; ++ni)
                    acc[mi][ni] = __builtin_amdgcn_mfma_f32_16x16x32_bf16(av[mi], bv[ni],
                                                                          acc[mi][ni], 0, 0, 0);
        }
        __syncthreads();
    }
    constexpr float LOG2E = 1.4426950408889634f;
    constexpr float LN2   = 0.6931471805599453f;
#pragma unroll
    for (int mi = 0; mi < MI; ++mi) {
#pragma unroll
        for (int ni = 0; ni < NI; ++ni) {
            int col = n0 + wn0 + ni * 16 + fr;
            float bb = bias ? bias[col] : 0.f;
#pragma unroll
            for (int j = 0; j < 4; ++j) {
                int row = m0 + wm0 + mi * 16 + fh * 4 + j;
                float v = acc[mi][ni][j] + bb;
                if (OUTMODE == 0)      Cf[(size_t)row * N + col] = v;
                else if (OUTMODE == 1) Cb[(size_t)row * N + col] = f2b(v);
                else if (OUTMODE == 4) {
                    Cf[(size_t)row * N + col] = v;
                    if (col < 32) {
                        unsigned short xh = f2b(v);
                        unsigned short xl = f2b(v - b2f(xh));
                        size_t base = (size_t)row * 128;
                        Cb[base + col]      = xh;
                        Cb[base + 32 + col] = xl;
                        Cb[base + 64 + col] = xh;
                        Cb[base + 96 + col] = xl;
                    }
                } else {
                    float sp = (v > 20.f) ? v : flog2(1.f + fexp2(v * LOG2E)) * LN2;
                    if (OUTMODE == 2) Cf[(size_t)row * N + col] = sp;
                    else              Cb[(size_t)row * N + col] = f2b(sp);
                }
            }
        }
    }
}

// ---------------------------------------------------------------------------
// assemble cat row-major (8192 x 1024) bf16: [0,512)=xu from P(bf16), rest=skip
__global__ __launch_bounds__(256) void k_assemble(const unsigned short* __restrict__ P,
                                                  const float* __restrict__ skip,
                                                  const float* __restrict__ up_b,
                                                  unsigned short* __restrict__ catbf) {
    int bx = blockIdx.x;
    int m = bx >> 2;
    int c = (bx & 3) * 256 + threadIdx.x;
    int b = m >> 10, t = m & 1023, j = t >> 1;
    float v;
    if (c < 512) {
        size_t rb = (size_t)((b << 9) + j) * 2048;
        if (t & 1) {                       // odd t: k=2 @ j, k=0 @ j+1
            v = b2f(P[rb + 1024 + c]);
            if (j + 1 < 512) v += b2f(P[rb + 2048 + c]);
        } else {                           // even t: k=3 @ j-1, k=1 @ j
            v = b2f(P[rb + 512 + c]);
            if (j >= 1) v += b2f(P[rb - 2048 + 1536 + c]);
        }
        v += up_b[c];
    } else {
        v = skip[(size_t)m * 512 + (c - 512)];
    }
    catbf[(size_t)m * 1024 + c] = f2b(v);
}

// LayerNorm over 512 (bf16 input), 4 rows per 256-block, writes bf16
__global__ __launch_bounds__(256) void k_ln(const unsigned short* __restrict__ merged,
                                            const float* __restrict__ w,
                                            const float* __restrict__ bvec,
                                            unsigned short* __restrict__ outb) {
    int row = blockIdx.x * 4 + (threadIdx.x >> 6);
    int lane = threadIdx.x & 63;
    const unsigned short* r = merged + (size_t)row * 512 + lane * 8;
    bf16x8 v = *(const bf16x8*)r;
    float xv[8];
#pragma unroll
    for (int e = 0; e < 8; ++e) xv[e] = b2f((unsigned short)v[e]);
    float s = 0.f, ss = 0.f;
#pragma unroll
    for (int e = 0; e < 8; ++e) { s += xv[e]; ss += xv[e] * xv[e]; }
#pragma unroll
    for (int m = 1; m < 64; m <<= 1) { s += __shfl_xor(s, m, 64); ss += __shfl_xor(ss, m, 64); }
    float mean = s * (1.f / 512.f);
    float var = ss * (1.f / 512.f) - mean * mean;
    float inv = rsqrtf(var + 1e-5f);
    unsigned short o8[8];
#pragma unroll
    for (int e = 0; e < 8; ++e) {
        int c = lane * 8 + e;
        o8[e] = f2b((xv[e] - mean) * inv * w[c] + bvec[c]);
    }
    *(int4*)(outb + (size_t)row * 512 + lane * 8) = *(const int4*)o8;
}

// causal depthwise conv K=4 + bias + silu; 4 channels/thread, bf16 in/out
__global__ __launch_bounds__(256) void k_conv(const unsigned short* __restrict__ xzb,
                                              const float* __restrict__ cw,
                                              const float* __restrict__ cb,
                                              unsigned short* __restrict__ xcb) {
    int i = blockIdx.x * 256 + threadIdx.x;   // 2.1M threads
    int m = i >> 8;
    int c0 = (i & 255) * 4;
    int l = m & 1023;
    float4 w0 = *(const float4*)(cw + (size_t)(c0 + 0) * 4);
    float4 w1 = *(const float4*)(cw + (size_t)(c0 + 1) * 4);
    float4 w2 = *(const float4*)(cw + (size_t)(c0 + 2) * 4);
    float4 w3 = *(const float4*)(cw + (size_t)(c0 + 3) * 4);
    float4 acc = *(const float4*)(cb + c0);
    const float* wp0 = (const float*)&w0;
    const float* wp1 = (const float*)&w1;
    const float* wp2 = (const float*)&w2;
    const float* wp3 = (const float*)&w3;
#pragma unroll
    for (int k = 0; k < 4; ++k) {
        int lp = l - 3 + k;
        if (lp >= 0) {
            ushort4 xv = *(const ushort4*)(xzb + (size_t)(m - l + lp) * 2048 + c0);
            acc.x = fmaf(wp0[k], b2f(xv.x), acc.x);
            acc.y = fmaf(wp1[k], b2f(xv.y), acc.y);
            acc.z = fmaf(wp2[k], b2f(xv.z), acc.z);
            acc.w = fmaf(wp3[k], b2f(xv.w), acc.w);
        }
    }
    ushort4 o = { f2b(silu(acc.x)), f2b(silu(acc.y)), f2b(silu(acc.z)), f2b(silu(acc.w)) };
    *(ushort4*)(xcb + (size_t)m * 1024 + c0) = o;
}

// ---------------------------------------------------------------------------
// Chunked selective scan.  L=1024 split into NC=32 chunks of CL=32.
// Thread = (b, d, chunk), 16 states in registers.  dt/u staged in LDS;
// A2 row + power flag loaded from precomputed table (k_prep).
// Power fast path: chain form a *= a1 (compiler pipelines it best; tree
// variant measured SLOWER in round 25).
// Summaries COMPRESSED: phase0 stores packed uint32 (bf16 a | bf16 h << 16);
// carry writes compact bf16 h_init; phase1 reads bf16 h_init.
constexpr int SCAN_NC = 32;
constexpr int SCAN_CL = 32;

template <int PHASE>
__global__ __launch_bounds__(256) void k_scan_chunk(
        const unsigned short* __restrict__ dtb, const unsigned short* __restrict__ xcb,
        const float* __restrict__ xdbl, const unsigned short* __restrict__ xzb,
        const float* __restrict__ A2tab, const int* __restrict__ powflag,
        const float* __restrict__ Dp,
        unsigned int* __restrict__ sum, const unsigned short* __restrict__ hinit,
        unsigned short* __restrict__ ybf) {
    constexpr int CL = SCAN_CL;
    const int tid = threadIdx.x;
    const int d0 = blockIdx.x * 256;
    const int d = d0 + tid;
    const int b = blockIdx.y, c = blockIdx.z;
    const size_t mbase = (size_t)b * 1024 + (size_t)c * CL;

    // bulk-stage chunk inputs into LDS (coalesced 16B chunks, all in flight):
    //   sBC: B/C slice of xdbl; sdt/su: this block's dt/u [CL][256] bf16.
    __shared__ float sBC[CL][32];
    __shared__ unsigned short sdt[CL][256];
    __shared__ unsigned short su[CL][256];
    {
        int row = tid >> 3, q = tid & 7;   // CL*8 == 256
        *(float4*)&sBC[row][q * 4] =
            *(const float4*)(xdbl + (mbase + row) * 64 + 32 + q * 4);
    }
    for (int i = tid; i < CL * 32; i += 256) {       // 32 rows x 32 16B-chunks
        int row = i >> 5, q = i & 31;
        const size_t g = (mbase + row) * 1024 + d0 + q * 8;
        *(int4*)&sdt[row][q * 8] = *(const int4*)(dtb + g);
        *(int4*)&su[row][q * 8]  = *(const int4*)(xcb + g);
    }
    __syncthreads();

    float A2[16], h[16];
#pragma unroll
    for (int s = 0; s < 16; s += 4)
        *(f32x4*)&A2[s] = *(const f32x4*)(A2tab + (size_t)d * 16 + s);
    const bool powok = powflag[d] != 0;

    const size_t sumbase = ((size_t)(b * SCAN_NC + c) << 14) + d * 16;
    if (PHASE == 0) {
#pragma unroll
        for (int s = 0; s < 16; ++s) h[s] = 0.f;
    } else {
#pragma unroll
        for (int s = 0; s < 16; s += 8) {
            bf16x8 hv = *(const bf16x8*)(hinit + sumbase + s);
#pragma unroll
            for (int j = 0; j < 8; ++j) h[s + j] = b2f((unsigned short)hv[j]);
        }
    }
    float dtsum = 0.f;
    const float Dv = (PHASE == 1) ? Dp[d] : 0.f;

    // z prefetch one step ahead (phase 1 only)
    float zv_n = 0.f;
    if (PHASE == 1) zv_n = b2f(xzb[mbase * 2048 + 1024 + d]);

#pragma unroll 2
    for (int l = 0; l < CL; ++l) {
        const size_t m = mbase + l;
        const float dtv_c = b2f(sdt[l][tid]);
        const float uv_c  = b2f(su[l][tid]);
        float zv;
        if (PHASE == 1) {
            zv = zv_n;
            if (l + 1 < CL) zv_n = b2f(xzb[(m + 1) * 2048 + 1024 + d]);
        }
        const float dtu = dtv_c * uv_c;
        if (PHASE == 0) dtsum += dtv_c;
        float Bv[16], Cv[16];
#pragma unroll
        for (int q = 0; q < 4; ++q) {
            *(float4*)&Bv[q * 4] = *(const float4*)&sBC[l][q * 4];
            if (PHASE == 1)
                *(float4*)&Cv[q * 4] = *(const float4*)&sBC[l][16 + q * 4];
        }
        float p = 0.f;
        if (powok) {
            const float a1 = fexp2(dtv_c * A2[0]);
            float a = a1;
#pragma unroll
            for (int s = 0; s < 16; ++s) {
                h[s] = fmaf(a, h[s], dtu * Bv[s]);
                if (PHASE == 1) p = fmaf(h[s], Cv[s], p);
                a *= a1;
            }
        } else {
#pragma unroll
            for (int s = 0; s < 16; ++s) {
                float a = fexp2(dtv_c * A2[s]);
                h[s] = fmaf(a, h[s], dtu * Bv[s]);
                if (PHASE == 1) p = fmaf(h[s], Cv[s], p);
            }
        }
        if (PHASE == 1) {
            ybf[m * 1024 + d] = f2b((p + Dv * uv_c) * silu(zv));
        }
    }
    if (PHASE == 0) {
        float aprod[16];
        if (powok) {
            const float ap1 = fexp2(A2[0] * dtsum);
            float a = ap1;
#pragma unroll
            for (int s = 0; s < 16; ++s) { aprod[s] = a; a *= ap1; }
        } else {
#pragma unroll
            for (int s = 0; s < 16; ++s) aprod[s] = fexp2(A2[s] * dtsum);
        }
        unsigned int pk[16];
#pragma unroll
        for (int s = 0; s < 16; ++s)
            pk[s] = (unsigned int)f2b(aprod[s]) | ((unsigned int)f2b(h[s]) << 16);
#pragma unroll
        for (int s = 0; s < 16; s += 4)
            *(uint4*)(sum + sumbase + s) = *(const uint4*)&pk[s];
    }
}

// carry scan over packed chunk summaries; writes compact bf16 h_init.
__global__ __launch_bounds__(256) void k_scan_carry(const unsigned int* __restrict__ sum,
                                                    unsigned short* __restrict__ hinit) {
    int i = blockIdx.x * 256 + threadIdx.x;   // (b, d*16+s)
    int b = i >> 14, ds = i & 16383;
    float h = 0.f;
    for (int c = 0; c < SCAN_NC; ++c) {
        size_t idx = ((size_t)(b * SCAN_NC + c) << 14) + ds;
        unsigned int u = sum[idx];
        float a = b2f((unsigned short)(u & 0xffffu));
        float f = b2f((unsigned short)(u >> 16));
        hinit[idx] = f2b(h);
        h = fmaf(a, h, f);
    }
}

// ---------------------------------------------------------------------------
extern "C" void kernel_launch(void* const* d_in, const int* in_sizes, int n_in,
                              void* d_out, int out_size, void* d_ws, size_t ws_size,
                              hipStream_t stream) {
    const float* x         = (const float*)d_in[0];
    const float* skip      = (const float*)d_in[1];
    const float* up_w      = (const float*)d_in[2];
    const float* up_b      = (const float*)d_in[3];
    const float* merge_w   = (const float*)d_in[4];
    const float* merge_b   = (const float*)d_in[5];
    const float* ln_w      = (const float*)d_in[6];
    const float* ln_b      = (const float*)d_in[7];
    const float* in_proj_w = (const float*)d_in[8];
    const float* conv_w    = (const float*)d_in[9];
    const float* conv_b    = (const float*)d_in[10];
    const float* x_proj_w  = (const float*)d_in[11];
    const float* dt_proj_w = (const float*)d_in[12];
    const float* dt_proj_b = (const float*)d_in[13];
    const float* A_log     = (const float*)d_in[14];
    const float* D_param   = (const float*)d_in[15];
    const float* out_proj_w= (const float*)d_in[16];
    float* out = (float*)d_out;

    char* ws = (char*)d_ws;
    size_t off = 0;
    auto alloc = [&](size_t bytes) { size_t r = off; off += (bytes + 255) & ~(size_t)255; return r; };

    // persistent
    unsigned short* upT  = (unsigned short*)(ws + alloc(2048ull * 512 * 2));
    unsigned short* mw   = (unsigned short*)(ws + alloc(512ull * 1024 * 2));
    unsigned short* ipw  = (unsigned short*)(ws + alloc(2ull * 2048 * 512 * 2));
    unsigned short* xpw  = (unsigned short*)(ws + alloc(2ull * 64 * 1024 * 2));
    unsigned short* opw  = (unsigned short*)(ws + alloc(2ull * 512 * 1024 * 2));
    unsigned short* xbf  = (unsigned short*)(ws + alloc(4096ull * 512 * 2));
    unsigned short* ubf  = (unsigned short*)(ws + alloc(8192ull * 512 * 2));
    float*          A2tab   = (float*)(ws + alloc(2048ull * 16 * 4));
    int*            powflag = (int*)(ws + alloc(2048ull * 4));
    // per-layer arena (stage-1 buffers aliased in)
    unsigned short* xzbf  = (unsigned short*)(ws + alloc(8192ull * 2048 * 2));
    unsigned short* xcbf  = (unsigned short*)(ws + alloc(8192ull * 1024 * 2));
    float*          xdbl  = (float*)(ws + alloc(8192ull * 64 * 4));
    unsigned short* dtbf  = (unsigned short*)(ws + alloc(8192ull * 1024 * 2));
    unsigned short* ybf   = (unsigned short*)(ws + alloc(8192ull * 1024 * 2));
    unsigned int*   scan_sum   = (unsigned int*)(ws + alloc((size_t)SCAN_NC * 8 * 16384 * 4));
    unsigned short* scan_hinit = (unsigned short*)(ws + alloc((size_t)SCAN_NC * 8 * 16384 * 2));
    unsigned short* dtpA  = (unsigned short*)(ws + alloc(8192ull * 128 * 2));
    unsigned short* dtpB  = (unsigned short*)(ws + alloc(2048ull * 128 * 2));
    unsigned short* P      = xzbf;                  // 16MB <= 32MB, dead before in_proj
    unsigned short* catbf  = dtbf;                  // 16MB == 16MB, dead before dt GEMM
    unsigned short* merged = xcbf;                  // 8MB <= 16MB, dead before conv

    // fused weight prep (cvts + dtpackB + A2 table, both layers)
    k_prep<<<6024, 256, 0, stream>>>(x, merge_w, in_proj_w, x_proj_w, out_proj_w,
                                     dt_proj_w, A_log, xbf, mw, ipw, xpw, opw, dtpB,
                                     A2tab, powflag);
    k_upT<<<dim3(16, 16, 4), dim3(32, 32), 0, stream>>>(up_w, upT);

    // stage 1: transposed-conv as GEMM (bf16 out), assemble cat, merge GEMM, LN
    k_gemm<128, 128, 1><<<dim3(16, 32), 256, 0, stream>>>(xbf, upT, nullptr, P, nullptr,
                                                          4096, 2048, 512);
    k_assemble<<<32768, 256, 0, stream>>>(P, skip, up_b, catbf);
    k_gemm<128, 128, 1><<<dim3(4, 64), 256, 0, stream>>>(catbf, mw, nullptr, merged, merge_b,
                                                         8192, 512, 1024);
    k_ln<<<2048, 256, 0, stream>>>(merged, ln_w, ln_b, ubf);

    // two mamba layers
    for (int li = 0; li < 2; ++li) {
        k_gemm<128, 128, 1><<<dim3(16, 64), 256, 0, stream>>>(ubf, ipw + (size_t)li * 2048 * 512,
                                                              nullptr, xzbf, nullptr, 8192, 2048, 512);
        k_conv<<<8192, 256, 0, stream>>>(xzbf, conv_w + li * 4096, conv_b + li * 1024, xcbf);
        // x_proj GEMM with fused dtpackA epilogue (cols<32 -> split-bf16 operand)
        k_gemm<64, 64, 4><<<dim3(1, 128), 256, 0, stream>>>(xcbf, xpw + (size_t)li * 64 * 1024,
                                                            xdbl, dtpA, nullptr, 8192, 64, 1024);
        // dt GEMM: exact split-bf16 (K=128) + fused hw-softplus -> bf16
        k_gemm<128, 64, 3><<<dim3(16, 64), 256, 0, stream>>>(dtpA, dtpB + (size_t)li * 1024 * 128,
                                                             nullptr, dtbf,
                                                             dt_proj_b + (size_t)li * 1024,
                                                             8192, 1024, 128);
        const float* A2l = A2tab + (size_t)li * 1024 * 16;
        const int*   pfl = powflag + (size_t)li * 1024;
        const float* Dl  = D_param + (size_t)li * 1024;
        k_scan_chunk<0><<<dim3(4, 8, SCAN_NC), 256, 0, stream>>>(
            dtbf, xcbf, xdbl, xzbf, A2l, pfl, Dl, scan_sum, scan_hinit, ybf);
        k_scan_carry<<<512, 256, 0, stream>>>(scan_sum, scan_hinit);
        k_scan_chunk<1><<<dim3(4, 8, SCAN_NC), 256, 0, stream>>>(
            dtbf, xcbf, xdbl, xzbf, A2l, pfl, Dl, scan_sum, scan_hinit, ybf);
        if (li == 0)
            k_gemm<128, 128, 1><<<dim3(4, 64), 256, 0, stream>>>(ybf, opw, nullptr, ubf, nullptr,
                                                                 8192, 512, 1024);
        else
            k_gemm<128, 128, 0><<<dim3(4, 64), 256, 0, stream>>>(ybf, opw + (size_t)512 * 1024,
                                                                 out, nullptr, nullptr, 8192, 512, 1024);
    }
}

// Round 29
// 403.028 us; speedup vs baseline: 1.0341x; 1.0032x over previous
//
#include <hip/hip_runtime.h>

#define DEV __device__ __forceinline__

typedef short  bf16x8 __attribute__((ext_vector_type(8)));
typedef float  f32x4  __attribute__((ext_vector_type(4)));

DEV unsigned short f2b(float f) {
    unsigned int u = __float_as_uint(f);
    u += 0x7fffu + ((u >> 16) & 1u);
    return (unsigned short)(u >> 16);
}
DEV float b2f(unsigned short h) { return __uint_as_float((unsigned int)h << 16); }
DEV float silu(float x) { return x / (1.f + __expf(-x)); }
DEV float fexp2(float x) { return __builtin_amdgcn_exp2f(x); }   // raw v_exp_f32
DEV float flog2(float x) { return __builtin_amdgcn_logf(x); }    // raw v_log_f32

// async global->LDS, 16B per lane: HW writes lane l at ldsbase + l*16
typedef const __attribute__((address_space(1))) unsigned int GU32;
typedef __attribute__((address_space(3))) unsigned int LU32;
DEV void gload16(const unsigned short* g, unsigned short* l) {
    __builtin_amdgcn_global_load_lds((GU32*)g, (LU32*)l, 16, 0, 0);
}

// ---------------------------------------------------------------------------
// fused prep: weight f32->bf16 conversions + dt_proj_w split-bf16 packing +
// scan A2 table (-exp(A_log)*log2e) with integer-power flag.
__global__ __launch_bounds__(256) void k_prep(
        const float* __restrict__ x, const float* __restrict__ merge_w,
        const float* __restrict__ in_proj_w, const float* __restrict__ x_proj_w,
        const float* __restrict__ out_proj_w, const float* __restrict__ dt_proj_w,
        const float* __restrict__ A_log,
        unsigned short* __restrict__ xbf, unsigned short* __restrict__ mw,
        unsigned short* __restrict__ ipw, unsigned short* __restrict__ xpw,
        unsigned short* __restrict__ opw, unsigned short* __restrict__ dtpB,
        float* __restrict__ A2tab, int* __restrict__ powflag) {
    size_t i = (size_t)blockIdx.x * 256 + threadIdx.x;
    const size_t n0 = 524288;           // x: 4096*512/4
    const size_t n1 = n0 + 131072;      // merge_w: 512*1024/4
    const size_t n2 = n1 + 524288;      // in_proj: 2*2048*512/4
    const size_t n3 = n2 + 32768;       // x_proj: 2*64*1024/4
    const size_t n4 = n3 + 262144;      // out_proj: 2*512*1024/4
    const size_t n5 = n4 + 65536;       // dtpackB: 2*1024*32 scalars
    const size_t n6 = n5 + 2048;        // A2 table: one thread per d (2 layers)
    if (i < n4) {
        const float* s; unsigned short* d; size_t j;
        if (i < n0)      { s = x;          d = xbf; j = i; }
        else if (i < n1) { s = merge_w;    d = mw;  j = i - n0; }
        else if (i < n2) { s = in_proj_w;  d = ipw; j = i - n1; }
        else if (i < n3) { s = x_proj_w;   d = xpw; j = i - n2; }
        else             { s = out_proj_w; d = opw; j = i - n3; }
        float4 v = *(const float4*)(s + j * 4);
        ushort4 o = { f2b(v.x), f2b(v.y), f2b(v.z), f2b(v.w) };
        *(ushort4*)(d + j * 4) = o;
    } else if (i < n5) {
        size_t j = i - n4;              // (li*1024+d)*32 + r
        int r = (int)(j & 31);
        size_t dg = j >> 5;             // global d in [0, 2048)
        float xw = dt_proj_w[dg * 32 + r];
        unsigned short wh = f2b(xw);
        unsigned short wl = f2b(xw - b2f(wh));
        size_t base = dg * 128;
        dtpB[base + r]      = wh;
        dtpB[base + 32 + r] = wl;
        dtpB[base + 64 + r] = wl;
        dtpB[base + 96 + r] = wh;
    } else if (i < n6) {
        size_t dg = i - n5;             // [0, 2048)
        constexpr float LOG2E = 1.4426950408889634f;
        float a2[16];
#pragma unroll
        for (int s = 0; s < 16; ++s)
            a2[s] = -expf(A_log[dg * 16 + s]) * LOG2E;
        bool ok = true;
#pragma unroll
        for (int s = 1; s < 16; ++s)
            ok = ok && (fabsf(a2[s] - (float)(s + 1) * a2[0]) <= 1e-5f * fabsf(a2[s]));
#pragma unroll
        for (int s = 0; s < 16; s += 4)
            *(f32x4*)(A2tab + dg * 16 + s) = *(const f32x4*)&a2[s];
        powflag[dg] = ok ? 1 : 0;
    }
}

// up_w (512 x 512 x 4) [i,o,k] -> upT[(k*512+o)*512 + i] bf16
__global__ void k_upT(const float* __restrict__ up_w, unsigned short* __restrict__ upT) {
    __shared__ float t[32][33];
    int tx = threadIdx.x, ty = threadIdx.y;
    int o0 = blockIdx.x * 32, i0 = blockIdx.y * 32, kz = blockIdx.z;
    t[ty][tx] = up_w[(size_t)(i0 + ty) * 2048 + (o0 + tx) * 4 + kz];
    __syncthreads();
    upT[(size_t)(kz * 512 + o0 + ty) * 512 + i0 + tx] = f2b(t[tx][ty]);
}

// ---------------------------------------------------------------------------
// bf16 MFMA GEMM, NT: C[m,n] = sum_k A[m,k]*B[n,k].  BK=64, 4 waves,
// global_load_lds staging with T2 XOR-swizzle (rule #21: linear LDS dest +
// inverse-swizzled GLOBAL source + swizzled READ).
// XCD-aware block swizzle (T1): contiguous tile chunks per XCD for L2 reuse.
// Tiles: (BM,BN) in {(128,128),(128,64),(64,64)}.
// OUTMODE 0: f32 out, 1: bf16 out, 2: softplus->f32, 3: softplus->bf16,
//         4: f32 out + dtpackA for cols<32 (split-bf16 K=128 operand).
template <int BM, int BN, int OUTMODE>
__global__ __launch_bounds__(256) void k_gemm(const unsigned short* __restrict__ A,
                                              const unsigned short* __restrict__ B,
                                              float* __restrict__ Cf,
                                              unsigned short* __restrict__ Cb,
                                              const float* __restrict__ bias,
                                              int M, int N, int K) {
    constexpr int BK = 64;
    constexpr int WM = (BN == 128) ? 64 : 32;
    constexpr int WN = (BM == 64 && BN == 64) ? 32 : 64;
    constexpr int MI = WM / 16, NI = WN / 16;
    __shared__ unsigned short As[BM * BK];
    __shared__ unsigned short Bs[BN * BK];
    const int tid = threadIdx.x;
    const int wid = tid >> 6, lane = tid & 63;

    // XCD swizzle: hw bids round-robin XCDs; map same-XCD bids to contiguous tiles
    int bid = blockIdx.y * gridDim.x + blockIdx.x;
    const int nwg = gridDim.x * gridDim.y;
    if ((nwg & 7) == 0) {
        int cpx = nwg >> 3;
        bid = (bid & 7) * cpx + (bid >> 3);
    }
    const int bx = bid % gridDim.x, by = bid / gridDim.x;
    const int m0 = by * BM, n0 = bx * BN;

    int wr, wc;
    if (BN == 128)      { wr = wid >> 1; wc = wid & 1; }
    else if (BM == 128) { wr = wid;      wc = 0;       }
    else                { wr = wid & 1;  wc = wid >> 1; }
    const int wm0 = wr * WM, wn0 = wc * WN;
    const int fr = lane & 15, fh = lane >> 4;

    // staging (BK=64): one gload16 covers 8 rows; lane l -> row (l>>3).
    // Global source col chunk pre-swizzled: chunk = (l&7) ^ (l>>3), because
    // staged rows step by 32 so (row & 7) == (l>>3) for this lane always.
    const int srow = lane >> 3;
    const int scol = (((lane & 7) ^ srow)) * 8;
    const unsigned short* Ag = A + (size_t)(m0 + wid * 8 + srow) * K + scol;
    const unsigned short* Bg = B + (size_t)(n0 + wid * 8 + srow) * K + scol;
    unsigned short* AsB = &As[wid * 8 * BK];
    unsigned short* BsB = &Bs[wid * 8 * BK];

    f32x4 acc[MI][NI];
#pragma unroll
    for (int i = 0; i < MI; ++i)
#pragma unroll
        for (int j = 0; j < NI; ++j) acc[i][j] = (f32x4){0.f, 0.f, 0.f, 0.f};

    const int frx = fr & 7;   // read-side XOR factor (row & 7)
    for (int k0 = 0; k0 < K; k0 += BK) {
#pragma unroll
        for (int i = 0; i < BM / 32; ++i)
            gload16(Ag + (size_t)(i * 32) * K + k0, AsB + i * 32 * BK);
#pragma unroll
        for (int i = 0; i < BN / 32; ++i)
            gload16(Bg + (size_t)(i * 32) * K + k0, BsB + i * 32 * BK);
        __syncthreads();
#pragma unroll
        for (int kk = 0; kk < BK; kk += 32) {
            bf16x8 av[MI], bv[NI];
#pragma unroll
            for (int mi = 0; mi < MI; ++mi)
                av[mi] = *(const bf16x8*)(&As[(wm0 + mi * 16 + fr) * BK +
                                              ((((kk >> 3) + fh) ^ frx) << 3)]);
#pragma unroll
            for (int ni = 0; ni < NI; ++ni)
                bv[ni] = *(const bf16x8*)(&Bs[(wn0 + ni * 16 + fr) * BK +
                                              ((((kk >> 3) + fh) ^ frx) << 3)]);
#pragma unroll
            for (int mi = 0; mi < MI; ++mi)
#pragma unroll
                for (int ni = 0; ni < NI; ++ni)
                    acc[mi][ni] = __builtin_amdgcn_mfma_f32_16x16x32_bf16(av[mi], bv[ni],
                                                                          acc[mi][ni], 0, 0, 0);
        }
        __syncthreads();
    }
    constexpr float LOG2E = 1.4426950408889634f;
    constexpr float LN2   = 0.6931471805599453f;
#pragma unroll
    for (int mi = 0; mi < MI; ++mi) {
#pragma unroll
        for (int ni = 0; ni < NI; ++ni) {
            int col = n0 + wn0 + ni * 16 + fr;
            float bb = bias ? bias[col] : 0.f;
#pragma unroll
            for (int j = 0; j < 4; ++j) {
                int row = m0 + wm0 + mi * 16 + fh * 4 + j;
                float v = acc[mi][ni][j] + bb;
                if (OUTMODE == 0)      Cf[(size_t)row * N + col] = v;
                else if (OUTMODE == 1) Cb[(size_t)row * N + col] = f2b(v);
                else if (OUTMODE == 4) {
                    Cf[(size_t)row * N + col] = v;
                    if (col < 32) {
                        unsigned short xh = f2b(v);
                        unsigned short xl = f2b(v - b2f(xh));
                        size_t base = (size_t)row * 128;
                        Cb[base + col]      = xh;
                        Cb[base + 32 + col] = xl;
                        Cb[base + 64 + col] = xh;
                        Cb[base + 96 + col] = xl;
                    }
                } else {
                    float sp = (v > 20.f) ? v : flog2(1.f + fexp2(v * LOG2E)) * LN2;
                    if (OUTMODE == 2) Cf[(size_t)row * N + col] = sp;
                    else              Cb[(size_t)row * N + col] = f2b(sp);
                }
            }
        }
    }
}

// ---------------------------------------------------------------------------
// assemble cat row-major (8192 x 1024) bf16: [0,512)=xu from P(bf16), rest=skip
// 8 columns/thread (vectorized loads + int4 store); branch uniform since the
// 512 boundary is a multiple of 8.  Per-element add order identical to scalar.
__global__ __launch_bounds__(256) void k_assemble(const unsigned short* __restrict__ P,
                                                  const float* __restrict__ skip,
                                                  const float* __restrict__ up_b,
                                                  unsigned short* __restrict__ catbf) {
    int i = blockIdx.x * 256 + threadIdx.x;   // 1M threads
    int m = i >> 7;
    int c0 = (i & 127) * 8;
    int b = m >> 10, t = m & 1023, j = t >> 1;
    unsigned short o8[8];
    if (c0 < 512) {
        size_t rb = (size_t)((b << 9) + j) * 2048;
        size_t off0, off1;
        bool two;
        if (t & 1) { off0 = rb + 1024 + c0; two = (j + 1 < 512); off1 = rb + 2048 + c0; }
        else       { off0 = rb + 512 + c0;  two = (j >= 1);      off1 = rb - 2048 + 1536 + c0; }
        bf16x8 p0 = *(const bf16x8*)(P + off0);
        float4 ub0 = *(const float4*)(up_b + c0);
        float4 ub1 = *(const float4*)(up_b + c0 + 4);
        float ub[8] = { ub0.x, ub0.y, ub0.z, ub0.w, ub1.x, ub1.y, ub1.z, ub1.w };
        if (two) {
            bf16x8 p1 = *(const bf16x8*)(P + off1);
#pragma unroll
            for (int e = 0; e < 8; ++e) {
                float v = b2f((unsigned short)p0[e]);
                v += b2f((unsigned short)p1[e]);
                v += ub[e];
                o8[e] = f2b(v);
            }
        } else {
#pragma unroll
            for (int e = 0; e < 8; ++e) {
                float v = b2f((unsigned short)p0[e]);
                v += ub[e];
                o8[e] = f2b(v);
            }
        }
    } else {
        float4 s0 = *(const float4*)(skip + (size_t)m * 512 + (c0 - 512));
        float4 s1 = *(const float4*)(skip + (size_t)m * 512 + (c0 - 512) + 4);
        float sv[8] = { s0.x, s0.y, s0.z, s0.w, s1.x, s1.y, s1.z, s1.w };
#pragma unroll
        for (int e = 0; e < 8; ++e) o8[e] = f2b(sv[e]);
    }
    *(int4*)(catbf + (size_t)m * 1024 + c0) = *(const int4*)o8;
}

// LayerNorm over 512 (bf16 input), 4 rows per 256-block, writes bf16
__global__ __launch_bounds__(256) void k_ln(const unsigned short* __restrict__ merged,
                                            const float* __restrict__ w,
                                            const float* __restrict__ bvec,
                                            unsigned short* __restrict__ outb) {
    int row = blockIdx.x * 4 + (threadIdx.x >> 6);
    int lane = threadIdx.x & 63;
    const unsigned short* r = merged + (size_t)row * 512 + lane * 8;
    bf16x8 v = *(const bf16x8*)r;
    float xv[8];
#pragma unroll
    for (int e = 0; e < 8; ++e) xv[e] = b2f((unsigned short)v[e]);
    float s = 0.f, ss = 0.f;
#pragma unroll
    for (int e = 0; e < 8; ++e) { s += xv[e]; ss += xv[e] * xv[e]; }
#pragma unroll
    for (int m = 1; m < 64; m <<= 1) { s += __shfl_xor(s, m, 64); ss += __shfl_xor(ss, m, 64); }
    float mean = s * (1.f / 512.f);
    float var = ss * (1.f / 512.f) - mean * mean;
    float inv = rsqrtf(var + 1e-5f);
    unsigned short o8[8];
#pragma unroll
    for (int e = 0; e < 8; ++e) {
        int c = lane * 8 + e;
        o8[e] = f2b((xv[e] - mean) * inv * w[c] + bvec[c]);
    }
    *(int4*)(outb + (size_t)row * 512 + lane * 8) = *(const int4*)o8;
}

// causal depthwise conv K=4 + bias + silu; 8 channels/thread, bf16x8 loads
__global__ __launch_bounds__(256) void k_conv(const unsigned short* __restrict__ xzb,
                                              const float* __restrict__ cw,
                                              const float* __restrict__ cb,
                                              unsigned short* __restrict__ xcb) {
    int i = blockIdx.x * 256 + threadIdx.x;   // 1M threads
    int m = i >> 7;
    int c0 = (i & 127) * 8;
    int l = m & 1023;
    float w[8][4];
#pragma unroll
    for (int jj = 0; jj < 8; ++jj) {
        float4 wv = *(const float4*)(cw + (size_t)(c0 + jj) * 4);
        w[jj][0] = wv.x; w[jj][1] = wv.y; w[jj][2] = wv.z; w[jj][3] = wv.w;
    }
    float acc[8];
    {
        float4 b0 = *(const float4*)(cb + c0);
        float4 b1 = *(const float4*)(cb + c0 + 4);
        acc[0] = b0.x; acc[1] = b0.y; acc[2] = b0.z; acc[3] = b0.w;
        acc[4] = b1.x; acc[5] = b1.y; acc[6] = b1.z; acc[7] = b1.w;
    }
#pragma unroll
    for (int k = 0; k < 4; ++k) {
        int lp = l - 3 + k;
        if (lp >= 0) {
            bf16x8 xv = *(const bf16x8*)(xzb + (size_t)(m - l + lp) * 2048 + c0);
#pragma unroll
            for (int jj = 0; jj < 8; ++jj)
                acc[jj] = fmaf(w[jj][k], b2f((unsigned short)xv[jj]), acc[jj]);
        }
    }
    unsigned short o8[8];
#pragma unroll
    for (int jj = 0; jj < 8; ++jj) o8[jj] = f2b(silu(acc[jj]));
    *(int4*)(xcb + (size_t)m * 1024 + c0) = *(const int4*)o8;
}

// ---------------------------------------------------------------------------
// Chunked selective scan.  L=1024 split into NC=32 chunks of CL=32.
// Thread = (b, d, chunk), 16 states in registers.  dt/u staged in LDS;
// A2 row + power flag loaded from precomputed table (k_prep).
// Power fast path: chain form a *= a1 (compiler pipelines it best; tree
// variant measured SLOWER in round 25).
// Summaries COMPRESSED: phase0 stores packed uint32 (bf16 a | bf16 h << 16);
// carry writes compact bf16 h_init; phase1 reads bf16 h_init.
constexpr int SCAN_NC = 32;
constexpr int SCAN_CL = 32;

template <int PHASE>
__global__ __launch_bounds__(256) void k_scan_chunk(
        const unsigned short* __restrict__ dtb, const unsigned short* __restrict__ xcb,
        const float* __restrict__ xdbl, const unsigned short* __restrict__ xzb,
        const float* __restrict__ A2tab, const int* __restrict__ powflag,
        const float* __restrict__ Dp,
        unsigned int* __restrict__ sum, const unsigned short* __restrict__ hinit,
        unsigned short* __restrict__ ybf) {
    constexpr int CL = SCAN_CL;
    const int tid = threadIdx.x;
    const int d0 = blockIdx.x * 256;
    const int d = d0 + tid;
    const int b = blockIdx.y, c = blockIdx.z;
    const size_t mbase = (size_t)b * 1024 + (size_t)c * CL;

    // bulk-stage chunk inputs into LDS (coalesced 16B chunks, all in flight):
    //   sBC: B/C slice of xdbl; sdt/su: this block's dt/u [CL][256] bf16.
    __shared__ float sBC[CL][32];
    __shared__ unsigned short sdt[CL][256];
    __shared__ unsigned short su[CL][256];
    {
        int row = tid >> 3, q = tid & 7;   // CL*8 == 256
        *(float4*)&sBC[row][q * 4] =
            *(const float4*)(xdbl + (mbase + row) * 64 + 32 + q * 4);
    }
    for (int i = tid; i < CL * 32; i += 256) {       // 32 rows x 32 16B-chunks
        int row = i >> 5, q = i & 31;
        const size_t g = (mbase + row) * 1024 + d0 + q * 8;
        *(int4*)&sdt[row][q * 8] = *(const int4*)(dtb + g);
        *(int4*)&su[row][q * 8]  = *(const int4*)(xcb + g);
    }
    __syncthreads();

    float A2[16], h[16];
#pragma unroll
    for (int s = 0; s < 16; s += 4)
        *(f32x4*)&A2[s] = *(const f32x4*)(A2tab + (size_t)d * 16 + s);
    const bool powok = powflag[d] != 0;

    const size_t sumbase = ((size_t)(b * SCAN_NC + c) << 14) + d * 16;
    if (PHASE == 0) {
#pragma unroll
        for (int s = 0; s < 16; ++s) h[s] = 0.f;
    } else {
#pragma unroll
        for (int s = 0; s < 16; s += 8) {
            bf16x8 hv = *(const bf16x8*)(hinit + sumbase + s);
#pragma unroll
            for (int j = 0; j < 8; ++j) h[s + j] = b2f((unsigned short)hv[j]);
        }
    }
    float dtsum = 0.f;
    const float Dv = (PHASE == 1) ? Dp[d] : 0.f;

    // z prefetch one step ahead (phase 1 only)
    float zv_n = 0.f;
    if (PHASE == 1) zv_n = b2f(xzb[mbase * 2048 + 1024 + d]);

#pragma unroll 2
    for (int l = 0; l < CL; ++l) {
        const size_t m = mbase + l;
        const float dtv_c = b2f(sdt[l][tid]);
        const float uv_c  = b2f(su[l][tid]);
        float zv;
        if (PHASE == 1) {
            zv = zv_n;
            if (l + 1 < CL) zv_n = b2f(xzb[(m + 1) * 2048 + 1024 + d]);
        }
        const float dtu = dtv_c * uv_c;
        if (PHASE == 0) dtsum += dtv_c;
        float Bv[16], Cv[16];
#pragma unroll
        for (int q = 0; q < 4; ++q) {
            *(float4*)&Bv[q * 4] = *(const float4*)&sBC[l][q * 4];
            if (PHASE == 1)
                *(float4*)&Cv[q * 4] = *(const float4*)&sBC[l][16 + q * 4];
        }
        float p = 0.f;
        if (powok) {
            const float a1 = fexp2(dtv_c * A2[0]);
            float a = a1;
#pragma unroll
            for (int s = 0; s < 16; ++s) {
                h[s] = fmaf(a, h[s], dtu * Bv[s]);
                if (PHASE == 1) p = fmaf(h[s], Cv[s], p);
                a *= a1;
            }
        } else {
#pragma unroll
            for (int s = 0; s < 16; ++s) {
                float a = fexp2(dtv_c * A2[s]);
                h[s] = fmaf(a, h[s], dtu * Bv[s]);
                if (PHASE == 1) p = fmaf(h[s], Cv[s], p);
            }
        }
        if (PHASE == 1) {
            ybf[m * 1024 + d] = f2b((p + Dv * uv_c) * silu(zv));
        }
    }
    if (PHASE == 0) {
        float aprod[16];
        if (powok) {
            const float ap1 = fexp2(A2[0] * dtsum);
            float a = ap1;
#pragma unroll
            for (int s = 0; s < 16; ++s) { aprod[s] = a; a *= ap1; }
        } else {
#pragma unroll
            for (int s = 0; s < 16; ++s) aprod[s] = fexp2(A2[s] * dtsum);
        }
        unsigned int pk[16];
#pragma unroll
        for (int s = 0; s < 16; ++s)
            pk[s] = (unsigned int)f2b(aprod[s]) | ((unsigned int)f2b(h[s]) << 16);
#pragma unroll
        for (int s = 0; s < 16; s += 4)
            *(uint4*)(sum + sumbase + s) = *(const uint4*)&pk[s];
    }
}

// carry scan over packed chunk summaries; writes compact bf16 h_init.
__global__ __launch_bounds__(256) void k_scan_carry(const unsigned int* __restrict__ sum,
                                                    unsigned short* __restrict__ hinit) {
    int i = blockIdx.x * 256 + threadIdx.x;   // (b, d*16+s)
    int b = i >> 14, ds = i & 16383;
    float h = 0.f;
    for (int c = 0; c < SCAN_NC; ++c) {
        size_t idx = ((size_t)(b * SCAN_NC + c) << 14) + ds;
        unsigned int u = sum[idx];
        float a = b2f((unsigned short)(u & 0xffffu));
        float f = b2f((unsigned short)(u >> 16));
        hinit[idx] = f2b(h);
        h = fmaf(a, h, f);
    }
}

// ---------------------------------------------------------------------------
extern "C" void kernel_launch(void* const* d_in, const int* in_sizes, int n_in,
                              void* d_out, int out_size, void* d_ws, size_t ws_size,
                              hipStream_t stream) {
    const float* x         = (const float*)d_in[0];
    const float* skip      = (const float*)d_in[1];
    const float* up_w      = (const float*)d_in[2];
    const float* up_b      = (const float*)d_in[3];
    const float* merge_w   = (const float*)d_in[4];
    const float* merge_b   = (const float*)d_in[5];
    const float* ln_w      = (const float*)d_in[6];
    const float* ln_b      = (const float*)d_in[7];
    const float* in_proj_w = (const float*)d_in[8];
    const float* conv_w    = (const float*)d_in[9];
    const float* conv_b    = (const float*)d_in[10];
    const float* x_proj_w  = (const float*)d_in[11];
    const float* dt_proj_w = (const float*)d_in[12];
    const float* dt_proj_b = (const float*)d_in[13];
    const float* A_log     = (const float*)d_in[14];
    const float* D_param   = (const float*)d_in[15];
    const float* out_proj_w= (const float*)d_in[16];
    float* out = (float*)d_out;

    char* ws = (char*)d_ws;
    size_t off = 0;
    auto alloc = [&](size_t bytes) { size_t r = off; off += (bytes + 255) & ~(size_t)255; return r; };

    // persistent
    unsigned short* upT  = (unsigned short*)(ws + alloc(2048ull * 512 * 2));
    unsigned short* mw   = (unsigned short*)(ws + alloc(512ull * 1024 * 2));
    unsigned short* ipw  = (unsigned short*)(ws + alloc(2ull * 2048 * 512 * 2));
    unsigned short* xpw  = (unsigned short*)(ws + alloc(2ull * 64 * 1024 * 2));
    unsigned short* opw  = (unsigned short*)(ws + alloc(2ull * 512 * 1024 * 2));
    unsigned short* xbf  = (unsigned short*)(ws + alloc(4096ull * 512 * 2));
    unsigned short* ubf  = (unsigned short*)(ws + alloc(8192ull * 512 * 2));
    float*          A2tab   = (float*)(ws + alloc(2048ull * 16 * 4));
    int*            powflag = (int*)(ws + alloc(2048ull * 4));
    // per-layer arena (stage-1 buffers aliased in)
    unsigned short* xzbf  = (unsigned short*)(ws + alloc(8192ull * 2048 * 2));
    unsigned short* xcbf  = (unsigned short*)(ws + alloc(8192ull * 1024 * 2));
    float*          xdbl  = (float*)(ws + alloc(8192ull * 64 * 4));
    unsigned short* dtbf  = (unsigned short*)(ws + alloc(8192ull * 1024 * 2));
    unsigned short* ybf   = (unsigned short*)(ws + alloc(8192ull * 1024 * 2));
    unsigned int*   scan_sum   = (unsigned int*)(ws + alloc((size_t)SCAN_NC * 8 * 16384 * 4));
    unsigned short* scan_hinit = (unsigned short*)(ws + alloc((size_t)SCAN_NC * 8 * 16384 * 2));
    unsigned short* dtpA  = (unsigned short*)(ws + alloc(8192ull * 128 * 2));
    unsigned short* dtpB  = (unsigned short*)(ws + alloc(2048ull * 128 * 2));
    unsigned short* P      = xzbf;                  // 16MB <= 32MB, dead before in_proj
    unsigned short* catbf  = dtbf;                  // 16MB == 16MB, dead before dt GEMM
    unsigned short* merged = xcbf;                  // 8MB <= 16MB, dead before conv

    // fused weight prep (cvts + dtpackB + A2 table, both layers)
    k_prep<<<6024, 256, 0, stream>>>(x, merge_w, in_proj_w, x_proj_w, out_proj_w,
                                     dt_proj_w, A_log, xbf, mw, ipw, xpw, opw, dtpB,
                                     A2tab, powflag);
    k_upT<<<dim3(16, 16, 4), dim3(32, 32), 0, stream>>>(up_w, upT);

    // stage 1: transposed-conv as GEMM (bf16 out), assemble cat, merge GEMM, LN
    k_gemm<128, 128, 1><<<dim3(16, 32), 256, 0, stream>>>(xbf, upT, nullptr, P, nullptr,
                                                          4096, 2048, 512);
    k_assemble<<<4096, 256, 0, stream>>>(P, skip, up_b, catbf);
    k_gemm<128, 128, 1><<<dim3(4, 64), 256, 0, stream>>>(catbf, mw, nullptr, merged, merge_b,
                                                         8192, 512, 1024);
    k_ln<<<2048, 256, 0, stream>>>(merged, ln_w, ln_b, ubf);

    // two mamba layers
    for (int li = 0; li < 2; ++li) {
        k_gemm<128, 128, 1><<<dim3(16, 64), 256, 0, stream>>>(ubf, ipw + (size_t)li * 2048 * 512,
                                                              nullptr, xzbf, nullptr, 8192, 2048, 512);
        k_conv<<<4096, 256, 0, stream>>>(xzbf, conv_w + li * 4096, conv_b + li * 1024, xcbf);
        // x_proj GEMM with fused dtpackA epilogue (cols<32 -> split-bf16 operand)
        k_gemm<64, 64, 4><<<dim3(1, 128), 256, 0, stream>>>(xcbf, xpw + (size_t)li * 64 * 1024,
                                                            xdbl, dtpA, nullptr, 8192, 64, 1024);
        // dt GEMM: exact split-bf16 (K=128) + fused hw-softplus -> bf16
        k_gemm<128, 64, 3><<<dim3(16, 64), 256, 0, stream>>>(dtpA, dtpB + (size_t)li * 1024 * 128,
                                                             nullptr, dtbf,
                                                             dt_proj_b + (size_t)li * 1024,
                                                             8192, 1024, 128);
        const float* A2l = A2tab + (size_t)li * 1024 * 16;
        const int*   pfl = powflag + (size_t)li * 1024;
        const float* Dl  = D_param + (size_t)li * 1024;
        k_scan_chunk<0><<<dim3(4, 8, SCAN_NC), 256, 0, stream>>>(
            dtbf, xcbf, xdbl, xzbf, A2l, pfl, Dl, scan_sum, scan_hinit, ybf);
        k_scan_carry<<<512, 256, 0, stream>>>(scan_sum, scan_hinit);
        k_scan_chunk<1><<<dim3(4, 8, SCAN_NC), 256, 0, stream>>>(
            dtbf, xcbf, xdbl, xzbf, A2l, pfl, Dl, scan_sum, scan_hinit, ybf);
        if (li == 0)
            k_gemm<128, 128, 1><<<dim3(4, 64), 256, 0, stream>>>(ybf, opw, nullptr, ubf, nullptr,
                                                                 8192, 512, 1024);
        else
            k_gemm<128, 128, 0><<<dim3(4, 64), 256, 0, stream>>>(ybf, opw + (size_t)512 * 1024,
                                                                 out, nullptr, nullptr, 8192, 512, 1024);
    }
}